// Round 2
// baseline (787.972 us; speedup 1.0000x reference)
//
#include <hip/hip_runtime.h>

typedef __attribute__((ext_vector_type(8))) short short8;
typedef __attribute__((ext_vector_type(4))) float floatx4;

#define NHID 128
#define PADROW 136   // bf16 uA row stride: 272B, 16B-aligned b128, 2-way banks (free)
#define HPAD 132     // f32 hS row stride: mod 32 == 4 -> 2-way banks on q-groups (free)
#define EB 64        // edges (or nodes) per batch

__device__ __forceinline__ unsigned short f2bf(float x) {
  unsigned int u = __float_as_uint(x);
  u += 0x7FFFu + ((u >> 16) & 1u);          // RNE
  return (unsigned short)(u >> 16);
}

__device__ __forceinline__ unsigned int pack2(float a, float b) {
  return (unsigned int)f2bf(a) | ((unsigned int)f2bf(b) << 16);
}

// 32 loop-invariant B-fragments (mfma_f32_16x16x32_bf16) of a 128x128
// row-major f32 weight. B[k][n]: lane holds n=16*nt+(lane&15), k=32*kc+q*8+j.
__device__ __forceinline__ void load_bfrags(const float* __restrict__ wmat,
                                            short8* bf, int m, int q) {
  #pragma unroll
  for (int kc = 0; kc < 4; ++kc) {
    #pragma unroll
    for (int nt = 0; nt < 8; ++nt) {
      short8 v;
      #pragma unroll
      for (int j = 0; j < 8; ++j)
        v[j] = (short)f2bf(wmat[(kc * 32 + q * 8 + j) * NHID + nt * 16 + m]);
      bf[kc * 8 + nt] = v;
    }
  }
}

// C[64 x 128] += A(LDS uA) * B(regs). Wave w owns rows 16w..16w+15.
__device__ __forceinline__ void mfma_block(const unsigned short* uA,
                                           const short8* bf, floatx4* acc,
                                           int w, int m, int q) {
  #pragma unroll
  for (int kc = 0; kc < 4; ++kc) {
    short8 a = *(const short8*)(uA + (16 * w + m) * PADROW + kc * 32 + q * 8);
    #pragma unroll
    for (int nt = 0; nt < 8; ++nt)
      acc[nt] = __builtin_amdgcn_mfma_f32_16x16x32_bf16(a, bf[kc * 8 + nt],
                                                        acc[nt], 0, 0, 0);
  }
}

// int64-vs-int32 edge_index probe (odd int32 slots all zero <=> int64).
__global__ void detect_kernel(const int* __restrict__ ei, int* __restrict__ flag) {
  unsigned long long b = __ballot(ei[2 * threadIdx.x + 1] != 0);
  if (threadIdx.x == 0) flag[0] = (b == 0ULL) ? 1 : 0;
}

__global__ void zero_kernel(float4* __restrict__ p, int n4) {
  int i = blockIdx.x * blockDim.x + threadIdx.x;
  int stride = gridDim.x * blockDim.x;
  float4 z = make_float4(0.f, 0.f, 0.f, 0.f);
  for (; i < n4; i += stride) p[i] = z;
}

// ---------------- counting sort by dst ----------------

__global__ void hist_kernel(const int* __restrict__ ei, const int* __restrict__ flag,
                            int* __restrict__ cnt, int E) {
  const bool is64 = flag[0] != 0;
  int i = blockIdx.x * blockDim.x + threadIdx.x;
  const int st = gridDim.x * blockDim.x;
  for (; i < E; i += st) {
    int d = is64 ? ei[2 * E + 2 * i] : ei[E + i];
    atomicAdd(&cnt[d], 1);
  }
}

// pass A: 1024 elements/block, in-place exclusive scan within block + block sums
__global__ void scan_a(int* __restrict__ cnt, int* __restrict__ bsums, int N) {
  __shared__ int sh[256];
  const int t = threadIdx.x;
  const int base = blockIdx.x * 1024 + t * 4;
  int v0 = (base     < N) ? cnt[base]     : 0;
  int v1 = (base + 1 < N) ? cnt[base + 1] : 0;
  int v2 = (base + 2 < N) ? cnt[base + 2] : 0;
  int v3 = (base + 3 < N) ? cnt[base + 3] : 0;
  sh[t] = v0 + v1 + v2 + v3;
  __syncthreads();
  for (int off = 1; off < 256; off <<= 1) {
    int x = (t >= off) ? sh[t - off] : 0;
    __syncthreads();
    sh[t] += x;
    __syncthreads();
  }
  int excl = (t > 0) ? sh[t - 1] : 0;
  if (base     < N) cnt[base]     = excl;
  if (base + 1 < N) cnt[base + 1] = excl + v0;
  if (base + 2 < N) cnt[base + 2] = excl + v0 + v1;
  if (base + 3 < N) cnt[base + 3] = excl + v0 + v1 + v2;
  if (t == 0) bsums[blockIdx.x] = sh[255];
}

// pass B: exclusive scan of <=256 block sums, single block
__global__ void scan_b(int* __restrict__ bsums, int nb) {
  __shared__ int sh[256];
  const int t = threadIdx.x;
  int v = (t < nb) ? bsums[t] : 0;
  sh[t] = v;
  __syncthreads();
  for (int off = 1; off < 256; off <<= 1) {
    int x = (t >= off) ? sh[t - off] : 0;
    __syncthreads();
    sh[t] += x;
    __syncthreads();
  }
  if (t < nb) bsums[t] = sh[t] - v;
}

__global__ void scan_c(int* __restrict__ cnt, const int* __restrict__ bsums, int N) {
  int i = blockIdx.x * blockDim.x + threadIdx.x;
  const int st = gridDim.x * blockDim.x;
  for (; i < N; i += st) cnt[i] += bsums[i >> 10];
}

__global__ void scatter_kernel(const int* __restrict__ ei, const int* __restrict__ flag,
                               int* __restrict__ offs, int2* __restrict__ sorted, int E) {
  const bool is64 = flag[0] != 0;
  int i = blockIdx.x * blockDim.x + threadIdx.x;
  const int st = gridDim.x * blockDim.x;
  for (; i < E; i += st) {
    int s = is64 ? ei[2 * i]         : ei[i];
    int d = is64 ? ei[2 * E + 2 * i] : ei[E + i];
    int p = atomicAdd(&offs[d], 1);
    sorted[p] = make_int2(s, d);
  }
}

// ---------------- edge MLP + segmented max over sorted edges ----------------

__global__ __launch_bounds__(256, 2) void edge_sorted_kernel(
    const float* __restrict__ x, const int2* __restrict__ sorted,
    const float* __restrict__ w1, const float* __restrict__ b1,
    const float* __restrict__ w2, const float* __restrict__ b2,
    float* agg, int N, int E) {
  __shared__ unsigned short uA[EB * PADROW];
  __shared__ float hS[EB * HPAD];
  __shared__ float w1s[6 * NHID];
  __shared__ float b1s[NHID], b2s[NHID];
  __shared__ int es[EB], ed[EB];
  __shared__ int pn[2];   // dst of edge before/after this tile (-2 = none)

  const int t = threadIdx.x;
  const int lane = t & 63;
  const int w = t >> 6;
  const int m = lane & 15;
  const int q = lane >> 4;

  for (int i = t; i < 6 * NHID; i += 256) w1s[i] = w1[i];
  if (t < NHID) { b1s[t] = b1[t]; b2s[t] = b2[t]; }

  short8 bf[32];
  load_bfrags(w2, bf, m, q);

  const int nb = (E + EB - 1) / EB;
  for (int batch = blockIdx.x; batch < nb; batch += gridDim.x) {
    const int gbase = batch * EB;
    if (t < EB) {
      int e = gbase + t;
      if (e < E) { int2 v = sorted[e]; es[t] = v.x; ed[t] = v.y; }
      else       { es[t] = 0; ed[t] = -1; }
    } else if (t == EB) {
      pn[0] = (gbase > 0) ? sorted[gbase - 1].y : -2;
    } else if (t == EB + 1) {
      pn[1] = (gbase + EB < E) ? sorted[gbase + EB].y : -2;
    }
    __syncthreads();

    // stage 1: u = relu([xi, xj-xi] @ w1 + b1) -> bf16 uA
    {
      const int e = t >> 2;
      const int c0 = (t & 3) * 32;
      const int si = es[e];
      const int di = (ed[e] < 0) ? 0 : ed[e];
      float xi0 = x[di * 3], xi1 = x[di * 3 + 1], xi2 = x[di * 3 + 2];
      float msg[6];
      msg[0] = xi0; msg[1] = xi1; msg[2] = xi2;
      msg[3] = x[si * 3] - xi0; msg[4] = x[si * 3 + 1] - xi1; msg[5] = x[si * 3 + 2] - xi2;
      unsigned int* d32 = (unsigned int*)uA;
      const int base32 = (e * PADROW + c0) >> 1;
      #pragma unroll
      for (int cc = 0; cc < 32; cc += 2) {
        float u0 = b1s[c0 + cc], u1 = b1s[c0 + cc + 1];
        #pragma unroll
        for (int d = 0; d < 6; ++d) {
          u0 += msg[d] * w1s[d * NHID + c0 + cc];
          u1 += msg[d] * w1s[d * NHID + c0 + cc + 1];
        }
        d32[base32 + (cc >> 1)] = pack2(fmaxf(u0, 0.f), fmaxf(u1, 0.f));
      }
    }
    __syncthreads();

    // stage 2: h = u @ w2 (+b2) -> LDS hS
    floatx4 acc[8];
    #pragma unroll
    for (int nt = 0; nt < 8; ++nt) { floatx4 z = {0.f, 0.f, 0.f, 0.f}; acc[nt] = z; }
    mfma_block(uA, bf, acc, w, m, q);

    #pragma unroll
    for (int nt = 0; nt < 8; ++nt) {
      const int c = nt * 16 + m;
      const float bb = b2s[c];
      #pragma unroll
      for (int r = 0; r < 4; ++r)
        hS[(16 * w + q * 4 + r) * HPAD + c] = acc[nt][r] + bb;
    }
    __syncthreads();

    // stage 3: segmented max over sorted dst runs. One thread per column.
    if (t < NHID) {
      const int c = t;
      const int prevd = pn[0], nextd = pn[1];
      float run = -1e30f;
      int cur = -3, rs = 0;
      #pragma unroll 4
      for (int r = 0; r <= EB; ++r) {
        const int d = (r < EB) ? ed[r] : -2;
        if (d != cur) {
          if (cur >= 0) {
            const float v = fmaxf(run, 0.f);
            const bool interior = (rs > 0 || prevd != cur) && (r < EB || nextd != cur);
            const size_t a = (size_t)cur * NHID + c;
            if (interior) agg[a] = v;
            else atomicMax((unsigned int*)(agg + a), __float_as_uint(v));
          }
          cur = d; rs = r; run = -1e30f;
        }
        if (r < EB) run = fmaxf(run, hS[r * HPAD + c]);
      }
    }
    __syncthreads();  // protect es/ed/uA/hS before next iteration
  }
}

// ---------------- fallback: R1 atomic edge kernel (small ws) ----------------

__global__ __launch_bounds__(256, 2) void edge_atomic_kernel(
    const float* __restrict__ x, const int* __restrict__ ei,
    const float* __restrict__ w1, const float* __restrict__ b1,
    const float* __restrict__ w2, const float* __restrict__ b2,
    float* agg, const int* __restrict__ flag64, int N, int E) {
  __shared__ unsigned short uA[EB * PADROW];
  __shared__ float w1s[6 * NHID];
  __shared__ float b1s[NHID], b2s[NHID];
  __shared__ int es[EB], ed[EB];

  const int t = threadIdx.x;
  const int lane = t & 63;
  const int w = t >> 6;
  const int m = lane & 15;
  const int q = lane >> 4;

  for (int i = t; i < 6 * NHID; i += 256) w1s[i] = w1[i];
  if (t < NHID) { b1s[t] = b1[t]; b2s[t] = b2[t]; }

  short8 bf[32];
  load_bfrags(w2, bf, m, q);

  const bool is64 = (flag64[0] != 0);
  const int nb = (E + EB - 1) / EB;

  for (int batch = blockIdx.x; batch < nb; batch += gridDim.x) {
    const int gbase = batch * EB;
    if (t < EB) {
      int e = gbase + t;
      es[t] = (e < E) ? (is64 ? ei[2 * e] : ei[e]) : 0;
    } else if (t < 2 * EB) {
      int tt = t - EB;
      int e = gbase + tt;
      ed[tt] = (e < E) ? (is64 ? ei[2 * E + 2 * e] : ei[E + e]) : 0;
    }
    __syncthreads();
    {
      const int e = t >> 2;
      const int c0 = (t & 3) * 32;
      const int si = es[e], di = ed[e];
      float xi0 = x[di * 3], xi1 = x[di * 3 + 1], xi2 = x[di * 3 + 2];
      float msg[6];
      msg[0] = xi0; msg[1] = xi1; msg[2] = xi2;
      msg[3] = x[si * 3] - xi0; msg[4] = x[si * 3 + 1] - xi1; msg[5] = x[si * 3 + 2] - xi2;
      unsigned int* d32 = (unsigned int*)uA;
      const int base32 = (e * PADROW + c0) >> 1;
      #pragma unroll
      for (int cc = 0; cc < 32; cc += 2) {
        float u0 = b1s[c0 + cc], u1 = b1s[c0 + cc + 1];
        #pragma unroll
        for (int d = 0; d < 6; ++d) {
          u0 += msg[d] * w1s[d * NHID + c0 + cc];
          u1 += msg[d] * w1s[d * NHID + c0 + cc + 1];
        }
        d32[base32 + (cc >> 1)] = pack2(fmaxf(u0, 0.f), fmaxf(u1, 0.f));
      }
    }
    __syncthreads();

    floatx4 acc[8];
    #pragma unroll
    for (int nt = 0; nt < 8; ++nt) { floatx4 z = {0.f, 0.f, 0.f, 0.f}; acc[nt] = z; }
    mfma_block(uA, bf, acc, w, m, q);

    #pragma unroll
    for (int nt = 0; nt < 8; ++nt) {
      const int c = nt * 16 + m;
      const float bb = b2s[c];
      #pragma unroll
      for (int r = 0; r < 4; ++r) {
        const int erow = 16 * w + q * 4 + r;
        if (gbase + erow < E) {
          float hb = acc[nt][r] + bb;
          if (hb > 0.f)
            atomicMax((unsigned int*)(agg + (size_t)ed[erow] * NHID + c),
                      __float_as_uint(hb));
        }
      }
    }
    __syncthreads();
  }
}

// ---------------- node MLPs ----------------

__global__ __launch_bounds__(256, 2) void enc_kernel(
    const float* __restrict__ w3, const float* __restrict__ b3,
    float* agg, int N) {
  __shared__ unsigned short uA[EB * PADROW];
  __shared__ float b3s[NHID];

  const int t = threadIdx.x;
  const int lane = t & 63;
  const int w = t >> 6;
  const int m = lane & 15;
  const int q = lane >> 4;

  if (t < NHID) b3s[t] = b3[t];
  short8 bf[32];
  load_bfrags(w3, bf, m, q);

  const int nb = (N + EB - 1) / EB;
  for (int batch = blockIdx.x; batch < nb; batch += gridDim.x) {
    const int base = batch * EB;
    __syncthreads();
    for (int i = t; i < EB * 32; i += 256) {
      const int row = i >> 5, c4 = i & 31;
      const int node = base + row;
      float4 v = make_float4(0.f, 0.f, 0.f, 0.f);
      if (node < N) v = ((const float4*)agg)[(size_t)node * 32 + c4];
      unsigned int* d32 = (unsigned int*)uA;
      const int o = row * (PADROW >> 1) + c4 * 2;
      d32[o] = pack2(v.x, v.y);
      d32[o + 1] = pack2(v.z, v.w);
    }
    __syncthreads();

    floatx4 acc[8];
    #pragma unroll
    for (int nt = 0; nt < 8; ++nt) { floatx4 z = {0.f, 0.f, 0.f, 0.f}; acc[nt] = z; }
    mfma_block(uA, bf, acc, w, m, q);

    #pragma unroll
    for (int nt = 0; nt < 8; ++nt) {
      const int c = nt * 16 + m;
      const float bb = b3s[c];
      #pragma unroll
      for (int r = 0; r < 4; ++r) {
        const int node = base + 16 * w + q * 4 + r;
        if (node < N) agg[(size_t)node * NHID + c] = acc[nt][r] + bb;
      }
    }
  }
}

__global__ __launch_bounds__(256, 2) void dec_kernel(
    const float* __restrict__ w4, const float* __restrict__ b4,
    const float* __restrict__ w5, const float* __restrict__ b5,
    const float* __restrict__ pos, const float* __restrict__ enc,
    float* __restrict__ out, int N) {
  __shared__ unsigned short uA[EB * PADROW];
  __shared__ float b4s[NHID];
  __shared__ float w5s[NHID * 3];

  const int t = threadIdx.x;
  const int lane = t & 63;
  const int w = t >> 6;
  const int m = lane & 15;
  const int q = lane >> 4;

  if (t < NHID) b4s[t] = b4[t];
  for (int i = t; i < NHID * 3; i += 256) w5s[i] = w5[i];
  short8 bf[32];
  load_bfrags(w4, bf, m, q);

  const int nb = (N + EB - 1) / EB;
  for (int batch = blockIdx.x; batch < nb; batch += gridDim.x) {
    const int base = batch * EB;
    __syncthreads();
    for (int i = t; i < EB * 32; i += 256) {
      const int row = i >> 5, c4 = i & 31;
      const int node = base + row;
      float4 v = make_float4(0.f, 0.f, 0.f, 0.f);
      if (node < N) v = ((const float4*)enc)[(size_t)node * 32 + c4];
      unsigned int* d32 = (unsigned int*)uA;
      const int o = row * (PADROW >> 1) + c4 * 2;
      d32[o] = pack2(v.x, v.y);
      d32[o + 1] = pack2(v.z, v.w);
    }
    __syncthreads();

    floatx4 acc[8];
    #pragma unroll
    for (int nt = 0; nt < 8; ++nt) { floatx4 z = {0.f, 0.f, 0.f, 0.f}; acc[nt] = z; }
    mfma_block(uA, bf, acc, w, m, q);

    float p[4][3];
    #pragma unroll
    for (int r = 0; r < 4; ++r) { p[r][0] = 0.f; p[r][1] = 0.f; p[r][2] = 0.f; }
    #pragma unroll
    for (int nt = 0; nt < 8; ++nt) {
      const int c = nt * 16 + m;
      const float bb = b4s[c];
      const float w50 = w5s[c * 3], w51 = w5s[c * 3 + 1], w52 = w5s[c * 3 + 2];
      #pragma unroll
      for (int r = 0; r < 4; ++r) {
        float tv = fmaxf(acc[nt][r] + bb, 0.f);
        p[r][0] += tv * w50; p[r][1] += tv * w51; p[r][2] += tv * w52;
      }
    }
    #pragma unroll
    for (int off = 8; off >= 1; off >>= 1) {
      #pragma unroll
      for (int r = 0; r < 4; ++r) {
        p[r][0] += __shfl_xor(p[r][0], off, 16);
        p[r][1] += __shfl_xor(p[r][1], off, 16);
        p[r][2] += __shfl_xor(p[r][2], off, 16);
      }
    }
    if (m == 0) {
      #pragma unroll
      for (int r = 0; r < 4; ++r) {
        const int node = base + 16 * w + q * 4 + r;
        if (node < N) {
          #pragma unroll
          for (int j = 0; j < 3; ++j) {
            float dec = p[r][j] + b5[j];
            out[node * 3 + j] = pos[node * 3 + j] + 0.1f * tanhf(dec);
          }
        }
      }
    }
  }
}

extern "C" void kernel_launch(void* const* d_in, const int* in_sizes, int n_in,
                              void* d_out, int out_size, void* d_ws, size_t ws_size,
                              hipStream_t stream) {
  const float* x   = (const float*)d_in[0];
  const float* pos = (const float*)d_in[1];
  const int*   ei  = (const int*)d_in[2];
  const float* w1  = (const float*)d_in[3];
  const float* b1  = (const float*)d_in[4];
  const float* w2  = (const float*)d_in[5];
  const float* b2  = (const float*)d_in[6];
  const float* w3  = (const float*)d_in[7];
  const float* b3  = (const float*)d_in[8];
  const float* w4  = (const float*)d_in[9];
  const float* b4  = (const float*)d_in[10];
  const float* w5  = (const float*)d_in[11];
  const float* b5  = (const float*)d_in[12];
  float* out = (float*)d_out;

  const int N = in_sizes[0] / 3;
  const int E = in_sizes[2] / 2;

  char* ws = (char*)d_ws;
  float* agg = (float*)ws;                                    // N*128 f32
  const size_t aggBytes = (size_t)N * NHID * sizeof(float);
  int*  cnt    = (int*)(ws + aggBytes);                       // N ints (hist -> offsets)
  int2* sorted = (int2*)(ws + aggBytes + (size_t)N * 4);      // E int2
  int*  bsums  = (int*)(ws + aggBytes + (size_t)N * 4 + (size_t)E * 8);
  int*  flag   = bsums + 1024;
  const size_t needed = aggBytes + (size_t)N * 4 + (size_t)E * 8 + 1024 * 4 + 16;
  const int nbA = (N + 1023) / 1024;

  if (ws_size >= needed && nbA <= 256) {
    detect_kernel<<<1, 64, 0, stream>>>(ei, flag);
    // zero agg + cnt (contiguous N*129 floats)
    zero_kernel<<<2048, 256, 0, stream>>>((float4*)agg, (N * 129 + 3) / 4);
    hist_kernel<<<512, 256, 0, stream>>>(ei, flag, cnt, E);
    scan_a<<<nbA, 256, 0, stream>>>(cnt, bsums, N);
    scan_b<<<1, 256, 0, stream>>>(bsums, nbA);
    scan_c<<<512, 256, 0, stream>>>(cnt, bsums, N);
    scatter_kernel<<<512, 256, 0, stream>>>(ei, flag, cnt, sorted, E);
    edge_sorted_kernel<<<512, 256, 0, stream>>>(x, sorted, w1, b1, w2, b2, agg, N, E);
  } else {
    int* flag2 = (int*)(ws + aggBytes);
    detect_kernel<<<1, 64, 0, stream>>>(ei, flag2);
    zero_kernel<<<2048, 256, 0, stream>>>((float4*)agg, N * NHID / 4);
    edge_atomic_kernel<<<512, 256, 0, stream>>>(x, ei, w1, b1, w2, b2, agg, flag2, N, E);
  }
  enc_kernel<<<512, 256, 0, stream>>>(w3, b3, agg, N);
  dec_kernel<<<512, 256, 0, stream>>>(w4, b4, w5, b5, pos, agg, out, N);
}

// Round 3
// 609.328 us; speedup vs baseline: 1.2932x; 1.2932x over previous
//
#include <hip/hip_runtime.h>
#include <hip/hip_bf16.h>

typedef __attribute__((ext_vector_type(8))) short short8;
typedef __attribute__((ext_vector_type(4))) float floatx4;

#define NHID 128
#define PADROW 136   // u16 row stride: 272B, 16B-aligned b128, benign banking
#define EB 64        // edges (or nodes) per tile

__device__ __forceinline__ unsigned short f2bf(float x) {
  unsigned int u = __float_as_uint(x);
  u += 0x7FFFu + ((u >> 16) & 1u);          // RNE
  return (unsigned short)(u >> 16);
}

// packed f32x2 -> bf16x2 (v_cvt_pk_bf16_f32 when available)
__device__ __forceinline__ unsigned int pkbf(float a, float b) {
  __hip_bfloat162 h = __float22bfloat162_rn(make_float2(a, b));
  union { __hip_bfloat162 h; unsigned int u; } cv;
  cv.h = h;
  return cv.u;
}

__device__ __forceinline__ unsigned int pack2(float a, float b) {
  return (unsigned int)f2bf(a) | ((unsigned int)f2bf(b) << 16);
}

// 32 loop-invariant B-fragments of a 128x128 row-major f32 weight (registers).
// B[k][n]: lane holds n=16*nt+(lane&15), k=32*kc+q*8+j.  (used by enc/dec)
__device__ __forceinline__ void load_bfrags(const float* __restrict__ wmat,
                                            short8* bf, int m, int q) {
  #pragma unroll
  for (int kc = 0; kc < 4; ++kc) {
    #pragma unroll
    for (int nt = 0; nt < 8; ++nt) {
      short8 v;
      #pragma unroll
      for (int j = 0; j < 8; ++j)
        v[j] = (short)f2bf(wmat[(kc * 32 + q * 8 + j) * NHID + nt * 16 + m]);
      bf[kc * 8 + nt] = v;
    }
  }
}

// C[64 x 128] += A(LDS uA) * B(regs). Wave w owns rows 16w..16w+15.
__device__ __forceinline__ void mfma_block(const unsigned short* uA,
                                           const short8* bf, floatx4* acc,
                                           int w, int m, int q) {
  #pragma unroll
  for (int kc = 0; kc < 4; ++kc) {
    short8 a = *(const short8*)(uA + (16 * w + m) * PADROW + kc * 32 + q * 8);
    #pragma unroll
    for (int nt = 0; nt < 8; ++nt)
      acc[nt] = __builtin_amdgcn_mfma_f32_16x16x32_bf16(a, bf[kc * 8 + nt],
                                                        acc[nt], 0, 0, 0);
  }
}

// zero agg+cnt; block 0 also runs the int64-vs-int32 edge_index probe.
__global__ void zero_detect_kernel(float4* __restrict__ p, int n4,
                                   const int* __restrict__ ei, int* __restrict__ flag) {
  if (blockIdx.x == 0 && threadIdx.x < 64) {
    unsigned long long b = __ballot(ei[2 * threadIdx.x + 1] != 0);
    if (threadIdx.x == 0) flag[0] = (b == 0ULL) ? 1 : 0;
  }
  int i = blockIdx.x * blockDim.x + threadIdx.x;
  int stride = gridDim.x * blockDim.x;
  float4 z = make_float4(0.f, 0.f, 0.f, 0.f);
  for (; i < n4; i += stride) p[i] = z;
}

// ---------------- counting sort by dst ----------------

__global__ void hist_kernel(const int* __restrict__ ei, const int* __restrict__ flag,
                            int* __restrict__ cnt, int E) {
  const bool is64 = flag[0] != 0;
  int i = blockIdx.x * blockDim.x + threadIdx.x;
  const int st = gridDim.x * blockDim.x;
  for (; i < E; i += st) {
    int d = is64 ? ei[2 * E + 2 * i] : ei[E + i];
    atomicAdd(&cnt[d], 1);
  }
}

__global__ void scan_a(int* __restrict__ cnt, int* __restrict__ bsums, int N) {
  __shared__ int sh[256];
  const int t = threadIdx.x;
  const int base = blockIdx.x * 1024 + t * 4;
  int v0 = (base     < N) ? cnt[base]     : 0;
  int v1 = (base + 1 < N) ? cnt[base + 1] : 0;
  int v2 = (base + 2 < N) ? cnt[base + 2] : 0;
  int v3 = (base + 3 < N) ? cnt[base + 3] : 0;
  sh[t] = v0 + v1 + v2 + v3;
  __syncthreads();
  for (int off = 1; off < 256; off <<= 1) {
    int x = (t >= off) ? sh[t - off] : 0;
    __syncthreads();
    sh[t] += x;
    __syncthreads();
  }
  int excl = (t > 0) ? sh[t - 1] : 0;
  if (base     < N) cnt[base]     = excl;
  if (base + 1 < N) cnt[base + 1] = excl + v0;
  if (base + 2 < N) cnt[base + 2] = excl + v0 + v1;
  if (base + 3 < N) cnt[base + 3] = excl + v0 + v1 + v2;
  if (t == 0) bsums[blockIdx.x] = sh[255];
}

__global__ void scan_b(int* __restrict__ bsums, int nb) {
  __shared__ int sh[256];
  const int t = threadIdx.x;
  int v = (t < nb) ? bsums[t] : 0;
  sh[t] = v;
  __syncthreads();
  for (int off = 1; off < 256; off <<= 1) {
    int x = (t >= off) ? sh[t - off] : 0;
    __syncthreads();
    sh[t] += x;
    __syncthreads();
  }
  if (t < nb) bsums[t] = sh[t] - v;
}

// scatter folds the chunk-offset add (formerly scan_c)
__global__ void scatter_kernel(const int* __restrict__ ei, const int* __restrict__ flag,
                               int* __restrict__ offs, const int* __restrict__ bsums,
                               int2* __restrict__ sorted, int E) {
  const bool is64 = flag[0] != 0;
  int i = blockIdx.x * blockDim.x + threadIdx.x;
  const int st = gridDim.x * blockDim.x;
  for (; i < E; i += st) {
    int s = is64 ? ei[2 * i]         : ei[i];
    int d = is64 ? ei[2 * E + 2 * i] : ei[E + i];
    int p = atomicAdd(&offs[d], 1) + bsums[d >> 10];
    sorted[p] = make_int2(s, d);
  }
}

// ---------------- fused edge MLP (both layers MFMA) + segmented max ----------------
// k-permutation: u's stored col kstore = m_w*8 + nt encodes true col c = 16*nt + m_w.
// w2 frags are built with the same permutation on k, so h = u @ w2 is unchanged.

__global__ __launch_bounds__(256, 3) void edge_sorted_kernel(
    const float* __restrict__ x, const int2* __restrict__ sorted,
    const float* __restrict__ w1, const float* __restrict__ b1,
    const float* __restrict__ w2, const float* __restrict__ b2,
    float* agg, int N, int E) {
  __shared__ unsigned short us[EB * PADROW];   // uA (layer-2 input), then hS (bf16)
  __shared__ short8 w2f[2048];                 // 32 frags x 64 lanes, k-permuted
  __shared__ int es[EB], ed[EB];
  __shared__ int pn[2];                        // dst before / after tile (-2 = none)
  __shared__ unsigned int pmerge[NHID];        // half-boundary partials

  const int t = threadIdx.x;
  const int lane = t & 63;
  const int w = t >> 6;
  const int m = lane & 15;
  const int q = lane >> 4;

  // per-lane column biases (c = 16*nt + m)
  float b1c[8], b2c[8];
  #pragma unroll
  for (int nt = 0; nt < 8; ++nt) { b1c[nt] = b1[nt * 16 + m]; b2c[nt] = b2[nt * 16 + m]; }

  // layer-1 B frags in VGPRs: B1[k][n] = w1[k][n] for k<6 else 0
  short8 bf1[8];
  #pragma unroll
  for (int nt = 0; nt < 8; ++nt) {
    short8 v;
    #pragma unroll
    for (int j = 0; j < 8; ++j)
      v[j] = (q == 0 && j < 6) ? (short)f2bf(w1[j * NHID + nt * 16 + m]) : (short)0;
    bf1[nt] = v;
  }

  // layer-2 B frags in LDS, k-permuted: B2[khw][n] = w2[pi(khw)][n]
  for (int idx = t; idx < 2048; idx += 256) {
    const int fg = idx >> 6, ln = idx & 63;
    const int mm = ln & 15, qq = ln >> 4;
    const int kc = fg >> 3, nt = fg & 7;
    short8 v;
    #pragma unroll
    for (int j = 0; j < 8; ++j) {
      const int khw = kc * 32 + qq * 8 + j;
      const int ctrue = ((khw & 7) << 4) | (khw >> 3);
      v[j] = (short)f2bf(w2[ctrue * NHID + nt * 16 + mm]);
    }
    w2f[idx] = v;
  }

  const int jcol = t & 127;                    // stage-3 stored column
  const int half = t >> 7;                     // stage-3 row half
  const int ctr3 = ((jcol & 7) << 4) | (jcol >> 3);

  const int nb = (E + EB - 1) / EB;
  __syncthreads();

  for (int batch = blockIdx.x; batch < nb; batch += gridDim.x) {
    const int gbase = batch * EB;
    if (t < EB) {
      int e = gbase + t;
      if (e < E) { int2 v = sorted[e]; es[t] = v.x; ed[t] = v.y; }
      else       { es[t] = 0; ed[t] = -1; }
    } else if (t == EB) {
      pn[0] = (gbase > 0) ? sorted[gbase - 1].y : -2;
    } else if (t == EB + 1) {
      pn[1] = (gbase + EB < E) ? sorted[gbase + EB].y : -2;
    }
    __syncthreads();   // A: es/ed ready

    // ---- layer 1: u = relu(msg @ w1 + b1) via MFMA ----
    floatx4 acc[8];
    #pragma unroll
    for (int nt = 0; nt < 8; ++nt) { floatx4 z = {0.f, 0.f, 0.f, 0.f}; acc[nt] = z; }
    short8 a1 = {0, 0, 0, 0, 0, 0, 0, 0};
    if (q == 0) {
      const int e = 16 * w + m;
      const int si = es[e];
      const int di = (ed[e] < 0) ? 0 : ed[e];
      float xi0 = x[di * 3], xi1 = x[di * 3 + 1], xi2 = x[di * 3 + 2];
      float d0 = x[si * 3] - xi0, d1 = x[si * 3 + 1] - xi1, d2 = x[si * 3 + 2] - xi2;
      union { short8 s; uint4 u; } cv;
      cv.u = make_uint4(pkbf(xi0, xi1), pkbf(xi2, d0), pkbf(d1, d2), 0u);
      a1 = cv.s;
    }
    #pragma unroll
    for (int nt = 0; nt < 8; ++nt)
      acc[nt] = __builtin_amdgcn_mfma_f32_16x16x32_bf16(a1, bf1[nt], acc[nt], 0, 0, 0);

    // epilogue 1: relu(+b1) -> bf16, k-permuted rows of uA (one b128 per row)
    #pragma unroll
    for (int r = 0; r < 4; ++r) {
      union { short8 s; uint4 u; } cv;
      cv.u = make_uint4(
        pkbf(fmaxf(acc[0][r] + b1c[0], 0.f), fmaxf(acc[1][r] + b1c[1], 0.f)),
        pkbf(fmaxf(acc[2][r] + b1c[2], 0.f), fmaxf(acc[3][r] + b1c[3], 0.f)),
        pkbf(fmaxf(acc[4][r] + b1c[4], 0.f), fmaxf(acc[5][r] + b1c[5], 0.f)),
        pkbf(fmaxf(acc[6][r] + b1c[6], 0.f), fmaxf(acc[7][r] + b1c[7], 0.f)));
      *(short8*)(us + (16 * w + q * 4 + r) * PADROW + m * 8) = cv.s;
    }
    __syncthreads();   // B: uA ready

    // ---- layer 2: h = u @ w2 (k-permuted on both sides) ----
    #pragma unroll
    for (int nt = 0; nt < 8; ++nt) { floatx4 z = {0.f, 0.f, 0.f, 0.f}; acc[nt] = z; }
    #pragma unroll
    for (int kc = 0; kc < 4; ++kc) {
      short8 a = *(const short8*)(us + (16 * w + m) * PADROW + kc * 32 + q * 8);
      #pragma unroll
      for (int nt = 0; nt < 8; ++nt)
        acc[nt] = __builtin_amdgcn_mfma_f32_16x16x32_bf16(a, w2f[(kc * 8 + nt) * 64 + lane],
                                                          acc[nt], 0, 0, 0);
    }
    __syncthreads();   // C: uA reads done (buffer about to be overwritten)

    // epilogue 2: clamp(h + b2, 0) -> bf16 hS (same k-permuted layout)
    #pragma unroll
    for (int r = 0; r < 4; ++r) {
      union { short8 s; uint4 u; } cv;
      cv.u = make_uint4(
        pkbf(fmaxf(acc[0][r] + b2c[0], 0.f), fmaxf(acc[1][r] + b2c[1], 0.f)),
        pkbf(fmaxf(acc[2][r] + b2c[2], 0.f), fmaxf(acc[3][r] + b2c[3], 0.f)),
        pkbf(fmaxf(acc[4][r] + b2c[4], 0.f), fmaxf(acc[5][r] + b2c[5], 0.f)),
        pkbf(fmaxf(acc[6][r] + b2c[6], 0.f), fmaxf(acc[7][r] + b2c[7], 0.f)));
      *(short8*)(us + (16 * w + q * 4 + r) * PADROW + m * 8) = cv.s;
    }
    __syncthreads();   // D: hS ready

    // ---- stage 3: segmented max, u16 domain, 2 row-halves x 128 cols ----
    {
      const int r0 = 32 * half, r1 = r0 + 32;
      const int ed31 = ed[31], ed32 = ed[32];
      const int prevd = pn[0], nextd = pn[1];
      unsigned int run = 0;
      int cur = -3, rs = r0;
      bool defer = false; unsigned int drun = 0; int dcur = -1, drs = 0;
      #pragma unroll 4
      for (int r = r0; r <= r1; ++r) {
        const int d = (r < r1) ? ed[r] : -2;
        if (d != cur) {
          if (cur >= 0) {
            const int re = r - 1;
            if (half == 0) {
              if (re == 31 && ed32 == cur) { defer = true; drun = run; dcur = cur; drs = rs; }
              else {
                const bool interior = (rs > 0 || prevd != cur);   // end side guaranteed interior
                const float v = __uint_as_float(run << 16);
                const size_t a = (size_t)cur * NHID + ctr3;
                if (interior) agg[a] = v;
                else atomicMax((unsigned int*)(agg + a), __float_as_uint(v));
              }
            } else {
              if (rs == 32 && ed31 == cur) {
                const unsigned int cont = (re == 63 && nextd == cur) ? 1u : 0u;
                pmerge[jcol] = run | (cont << 16);
              } else {
                const bool interior = !(re == 63 && nextd == cur); // start side interior
                const float v = __uint_as_float(run << 16);
                const size_t a = (size_t)cur * NHID + ctr3;
                if (interior) agg[a] = v;
                else atomicMax((unsigned int*)(agg + a), __float_as_uint(v));
              }
            }
          }
          cur = d; rs = r; run = 0;
        }
        if (r < r1) run = max(run, (unsigned int)us[r * PADROW + jcol]);
      }
      __syncthreads();   // E: pmerge posted
      if (half == 0 && defer) {
        const unsigned int pm = pmerge[jcol];
        const unsigned int comb = max(drun, pm & 0xFFFFu);
        const bool cont = (pm >> 16) != 0;
        const bool interior = (drs > 0 || prevd != dcur) && !cont;
        const float v = __uint_as_float(comb << 16);
        const size_t a = (size_t)dcur * NHID + ctr3;
        if (interior) agg[a] = v;
        else atomicMax((unsigned int*)(agg + a), __float_as_uint(v));
      }
    }
    __syncthreads();     // F: end of tile (protect es/ed/us)
  }
}

// ---------------- fallback: atomic edge kernel (small ws) ----------------

__global__ __launch_bounds__(256, 2) void edge_atomic_kernel(
    const float* __restrict__ x, const int* __restrict__ ei,
    const float* __restrict__ w1, const float* __restrict__ b1,
    const float* __restrict__ w2, const float* __restrict__ b2,
    float* agg, const int* __restrict__ flag64, int N, int E) {
  __shared__ unsigned short uA[EB * PADROW];
  __shared__ float w1s[6 * NHID];
  __shared__ float b1s[NHID], b2s[NHID];
  __shared__ int es[EB], ed[EB];

  const int t = threadIdx.x;
  const int lane = t & 63;
  const int w = t >> 6;
  const int m = lane & 15;
  const int q = lane >> 4;

  for (int i = t; i < 6 * NHID; i += 256) w1s[i] = w1[i];
  if (t < NHID) { b1s[t] = b1[t]; b2s[t] = b2[t]; }

  short8 bf[32];
  load_bfrags(w2, bf, m, q);

  const bool is64 = (flag64[0] != 0);
  const int nb = (E + EB - 1) / EB;

  for (int batch = blockIdx.x; batch < nb; batch += gridDim.x) {
    const int gbase = batch * EB;
    if (t < EB) {
      int e = gbase + t;
      es[t] = (e < E) ? (is64 ? ei[2 * e] : ei[e]) : 0;
    } else if (t < 2 * EB) {
      int tt = t - EB;
      int e = gbase + tt;
      ed[tt] = (e < E) ? (is64 ? ei[2 * E + 2 * e] : ei[E + e]) : 0;
    }
    __syncthreads();
    {
      const int e = t >> 2;
      const int c0 = (t & 3) * 32;
      const int si = es[e], di = ed[e];
      float xi0 = x[di * 3], xi1 = x[di * 3 + 1], xi2 = x[di * 3 + 2];
      float msg[6];
      msg[0] = xi0; msg[1] = xi1; msg[2] = xi2;
      msg[3] = x[si * 3] - xi0; msg[4] = x[si * 3 + 1] - xi1; msg[5] = x[si * 3 + 2] - xi2;
      unsigned int* d32 = (unsigned int*)uA;
      const int base32 = (e * PADROW + c0) >> 1;
      #pragma unroll
      for (int cc = 0; cc < 32; cc += 2) {
        float u0 = b1s[c0 + cc], u1 = b1s[c0 + cc + 1];
        #pragma unroll
        for (int d = 0; d < 6; ++d) {
          u0 += msg[d] * w1s[d * NHID + c0 + cc];
          u1 += msg[d] * w1s[d * NHID + c0 + cc + 1];
        }
        d32[base32 + (cc >> 1)] = pack2(fmaxf(u0, 0.f), fmaxf(u1, 0.f));
      }
    }
    __syncthreads();

    floatx4 acc[8];
    #pragma unroll
    for (int nt = 0; nt < 8; ++nt) { floatx4 z = {0.f, 0.f, 0.f, 0.f}; acc[nt] = z; }
    mfma_block(uA, bf, acc, w, m, q);

    #pragma unroll
    for (int nt = 0; nt < 8; ++nt) {
      const int c = nt * 16 + m;
      const float bb = b2s[c];
      #pragma unroll
      for (int r = 0; r < 4; ++r) {
        const int erow = 16 * w + q * 4 + r;
        if (gbase + erow < E) {
          float hb = acc[nt][r] + bb;
          if (hb > 0.f)
            atomicMax((unsigned int*)(agg + (size_t)ed[erow] * NHID + c),
                      __float_as_uint(hb));
        }
      }
    }
    __syncthreads();
  }
}

// ---------------- node MLPs ----------------

__global__ __launch_bounds__(256, 2) void enc_kernel(
    const float* __restrict__ w3, const float* __restrict__ b3,
    float* agg, int N) {
  __shared__ unsigned short uA[EB * PADROW];
  __shared__ float b3s[NHID];

  const int t = threadIdx.x;
  const int lane = t & 63;
  const int w = t >> 6;
  const int m = lane & 15;
  const int q = lane >> 4;

  if (t < NHID) b3s[t] = b3[t];
  short8 bf[32];
  load_bfrags(w3, bf, m, q);

  const int nb = (N + EB - 1) / EB;
  for (int batch = blockIdx.x; batch < nb; batch += gridDim.x) {
    const int base = batch * EB;
    __syncthreads();
    for (int i = t; i < EB * 32; i += 256) {
      const int row = i >> 5, c4 = i & 31;
      const int node = base + row;
      float4 v = make_float4(0.f, 0.f, 0.f, 0.f);
      if (node < N) v = ((const float4*)agg)[(size_t)node * 32 + c4];
      unsigned int* d32 = (unsigned int*)uA;
      const int o = row * (PADROW >> 1) + c4 * 2;
      d32[o] = pack2(v.x, v.y);
      d32[o + 1] = pack2(v.z, v.w);
    }
    __syncthreads();

    floatx4 acc[8];
    #pragma unroll
    for (int nt = 0; nt < 8; ++nt) { floatx4 z = {0.f, 0.f, 0.f, 0.f}; acc[nt] = z; }
    mfma_block(uA, bf, acc, w, m, q);

    #pragma unroll
    for (int nt = 0; nt < 8; ++nt) {
      const int c = nt * 16 + m;
      const float bb = b3s[c];
      #pragma unroll
      for (int r = 0; r < 4; ++r) {
        const int node = base + 16 * w + q * 4 + r;
        if (node < N) agg[(size_t)node * NHID + c] = acc[nt][r] + bb;
      }
    }
  }
}

__global__ __launch_bounds__(256, 2) void dec_kernel(
    const float* __restrict__ w4, const float* __restrict__ b4,
    const float* __restrict__ w5, const float* __restrict__ b5,
    const float* __restrict__ pos, const float* __restrict__ enc,
    float* __restrict__ out, int N) {
  __shared__ unsigned short uA[EB * PADROW];
  __shared__ float b4s[NHID];
  __shared__ float w5s[NHID * 3];

  const int t = threadIdx.x;
  const int lane = t & 63;
  const int w = t >> 6;
  const int m = lane & 15;
  const int q = lane >> 4;

  if (t < NHID) b4s[t] = b4[t];
  for (int i = t; i < NHID * 3; i += 256) w5s[i] = w5[i];
  short8 bf[32];
  load_bfrags(w4, bf, m, q);

  const int nb = (N + EB - 1) / EB;
  for (int batch = blockIdx.x; batch < nb; batch += gridDim.x) {
    const int base = batch * EB;
    __syncthreads();
    for (int i = t; i < EB * 32; i += 256) {
      const int row = i >> 5, c4 = i & 31;
      const int node = base + row;
      float4 v = make_float4(0.f, 0.f, 0.f, 0.f);
      if (node < N) v = ((const float4*)enc)[(size_t)node * 32 + c4];
      unsigned int* d32 = (unsigned int*)uA;
      const int o = row * (PADROW >> 1) + c4 * 2;
      d32[o] = pack2(v.x, v.y);
      d32[o + 1] = pack2(v.z, v.w);
    }
    __syncthreads();

    floatx4 acc[8];
    #pragma unroll
    for (int nt = 0; nt < 8; ++nt) { floatx4 z = {0.f, 0.f, 0.f, 0.f}; acc[nt] = z; }
    mfma_block(uA, bf, acc, w, m, q);

    float p[4][3];
    #pragma unroll
    for (int r = 0; r < 4; ++r) { p[r][0] = 0.f; p[r][1] = 0.f; p[r][2] = 0.f; }
    #pragma unroll
    for (int nt = 0; nt < 8; ++nt) {
      const int c = nt * 16 + m;
      const float bb = b4s[c];
      const float w50 = w5s[c * 3], w51 = w5s[c * 3 + 1], w52 = w5s[c * 3 + 2];
      #pragma unroll
      for (int r = 0; r < 4; ++r) {
        float tv = fmaxf(acc[nt][r] + bb, 0.f);
        p[r][0] += tv * w50; p[r][1] += tv * w51; p[r][2] += tv * w52;
      }
    }
    #pragma unroll
    for (int off = 8; off >= 1; off >>= 1) {
      #pragma unroll
      for (int r = 0; r < 4; ++r) {
        p[r][0] += __shfl_xor(p[r][0], off, 16);
        p[r][1] += __shfl_xor(p[r][1], off, 16);
        p[r][2] += __shfl_xor(p[r][2], off, 16);
      }
    }
    if (m == 0) {
      #pragma unroll
      for (int r = 0; r < 4; ++r) {
        const int node = base + 16 * w + q * 4 + r;
        if (node < N) {
          #pragma unroll
          for (int j = 0; j < 3; ++j) {
            float dec = p[r][j] + b5[j];
            out[node * 3 + j] = pos[node * 3 + j] + 0.1f * tanhf(dec);
          }
        }
      }
    }
  }
}

extern "C" void kernel_launch(void* const* d_in, const int* in_sizes, int n_in,
                              void* d_out, int out_size, void* d_ws, size_t ws_size,
                              hipStream_t stream) {
  const float* x   = (const float*)d_in[0];
  const float* pos = (const float*)d_in[1];
  const int*   ei  = (const int*)d_in[2];
  const float* w1  = (const float*)d_in[3];
  const float* b1  = (const float*)d_in[4];
  const float* w2  = (const float*)d_in[5];
  const float* b2  = (const float*)d_in[6];
  const float* w3  = (const float*)d_in[7];
  const float* b3  = (const float*)d_in[8];
  const float* w4  = (const float*)d_in[9];
  const float* b4  = (const float*)d_in[10];
  const float* w5  = (const float*)d_in[11];
  const float* b5  = (const float*)d_in[12];
  float* out = (float*)d_out;

  const int N = in_sizes[0] / 3;
  const int E = in_sizes[2] / 2;

  char* ws = (char*)d_ws;
  float* agg = (float*)ws;                                    // N*128 f32
  const size_t aggBytes = (size_t)N * NHID * sizeof(float);
  int*  cnt    = (int*)(ws + aggBytes);                       // N ints
  int2* sorted = (int2*)(ws + aggBytes + (size_t)N * 4);      // E int2
  int*  bsums  = (int*)(ws + aggBytes + (size_t)N * 4 + (size_t)E * 8);
  int*  flag   = bsums + 1024;
  const size_t needed = aggBytes + (size_t)N * 4 + (size_t)E * 8 + 1024 * 4 + 16;
  const int nbA = (N + 1023) / 1024;

  if (ws_size >= needed && nbA <= 256) {
    zero_detect_kernel<<<2048, 256, 0, stream>>>((float4*)agg, (N * 129 + 3) / 4, ei, flag);
    hist_kernel<<<2048, 256, 0, stream>>>(ei, flag, cnt, E);
    scan_a<<<nbA, 256, 0, stream>>>(cnt, bsums, N);
    scan_b<<<1, 256, 0, stream>>>(bsums, nbA);
    scatter_kernel<<<2048, 256, 0, stream>>>(ei, flag, cnt, bsums, sorted, E);
    edge_sorted_kernel<<<768, 256, 0, stream>>>(x, sorted, w1, b1, w2, b2, agg, N, E);
  } else {
    int* flag2 = (int*)(ws + aggBytes);
    zero_detect_kernel<<<2048, 256, 0, stream>>>((float4*)agg, N * NHID / 4, ei, flag2);
    edge_atomic_kernel<<<512, 256, 0, stream>>>(x, ei, w1, b1, w2, b2, agg, flag2, N, E);
  }
  enc_kernel<<<512, 256, 0, stream>>>(w3, b3, agg, N);
  dec_kernel<<<512, 256, 0, stream>>>(w4, b4, w5, b5, pos, agg, out, N);
}

// Round 4
// 527.759 us; speedup vs baseline: 1.4931x; 1.1546x over previous
//
#include <hip/hip_runtime.h>
#include <hip/hip_bf16.h>

typedef __attribute__((ext_vector_type(8))) short short8;
typedef __attribute__((ext_vector_type(4))) float floatx4;

#define NHID 128
#define PADROW 136   // u16 row stride: 272B, 16B-aligned b128, benign banking
#define EB 64        // edges (or nodes) per tile

__device__ __forceinline__ unsigned short f2bf(float x) {
  unsigned int u = __float_as_uint(x);
  u += 0x7FFFu + ((u >> 16) & 1u);          // RNE
  return (unsigned short)(u >> 16);
}

__device__ __forceinline__ unsigned int pkbf(float a, float b) {
  __hip_bfloat162 h = __float22bfloat162_rn(make_float2(a, b));
  union { __hip_bfloat162 h; unsigned int u; } cv;
  cv.h = h;
  return cv.u;
}

__device__ __forceinline__ unsigned int pack2(float a, float b) {
  return (unsigned int)f2bf(a) | ((unsigned int)f2bf(b) << 16);
}

// 32 loop-invariant B-fragments of a 128x128 row-major f32 weight (registers).
__device__ __forceinline__ void load_bfrags(const float* __restrict__ wmat,
                                            short8* bf, int m, int q) {
  #pragma unroll
  for (int kc = 0; kc < 4; ++kc) {
    #pragma unroll
    for (int nt = 0; nt < 8; ++nt) {
      short8 v;
      #pragma unroll
      for (int j = 0; j < 8; ++j)
        v[j] = (short)f2bf(wmat[(kc * 32 + q * 8 + j) * NHID + nt * 16 + m]);
      bf[kc * 8 + nt] = v;
    }
  }
}

__device__ __forceinline__ void mfma_block(const unsigned short* uA,
                                           const short8* bf, floatx4* acc,
                                           int w, int m, int q) {
  #pragma unroll
  for (int kc = 0; kc < 4; ++kc) {
    short8 a = *(const short8*)(uA + (16 * w + m) * PADROW + kc * 32 + q * 8);
    #pragma unroll
    for (int nt = 0; nt < 8; ++nt)
      acc[nt] = __builtin_amdgcn_mfma_f32_16x16x32_bf16(a, bf[kc * 8 + nt],
                                                        acc[nt], 0, 0, 0);
  }
}

// zero agg+cnt; block 0 also runs the int64-vs-int32 edge_index probe.
__global__ void zero_detect_kernel(float4* __restrict__ p, int n4,
                                   const int* __restrict__ ei, int* __restrict__ flag) {
  if (blockIdx.x == 0 && threadIdx.x < 64) {
    unsigned long long b = __ballot(ei[2 * threadIdx.x + 1] != 0);
    if (threadIdx.x == 0) flag[0] = (b == 0ULL) ? 1 : 0;
  }
  int i = blockIdx.x * blockDim.x + threadIdx.x;
  int stride = gridDim.x * blockDim.x;
  float4 z = make_float4(0.f, 0.f, 0.f, 0.f);
  for (; i < n4; i += stride) p[i] = z;
}

// ---------------- counting sort by dst ----------------

__global__ void hist_kernel(const int* __restrict__ ei, const int* __restrict__ flag,
                            int* __restrict__ cnt, int E) {
  const bool is64 = flag[0] != 0;
  int i = blockIdx.x * blockDim.x + threadIdx.x;
  const int st = gridDim.x * blockDim.x;
  for (; i < E; i += st) {
    int d = is64 ? ei[2 * E + 2 * i] : ei[E + i];
    atomicAdd(&cnt[d], 1);
  }
}

__global__ void scan_a(int* __restrict__ cnt, int* __restrict__ bsums, int N) {
  __shared__ int sh[256];
  const int t = threadIdx.x;
  const int base = blockIdx.x * 1024 + t * 4;
  int v0 = (base     < N) ? cnt[base]     : 0;
  int v1 = (base + 1 < N) ? cnt[base + 1] : 0;
  int v2 = (base + 2 < N) ? cnt[base + 2] : 0;
  int v3 = (base + 3 < N) ? cnt[base + 3] : 0;
  sh[t] = v0 + v1 + v2 + v3;
  __syncthreads();
  for (int off = 1; off < 256; off <<= 1) {
    int x = (t >= off) ? sh[t - off] : 0;
    __syncthreads();
    sh[t] += x;
    __syncthreads();
  }
  int excl = (t > 0) ? sh[t - 1] : 0;
  if (base     < N) cnt[base]     = excl;
  if (base + 1 < N) cnt[base + 1] = excl + v0;
  if (base + 2 < N) cnt[base + 2] = excl + v0 + v1;
  if (base + 3 < N) cnt[base + 3] = excl + v0 + v1 + v2;
  if (t == 0) bsums[blockIdx.x] = sh[255];
}

__global__ void scan_b(int* __restrict__ bsums, int nb) {
  __shared__ int sh[256];
  const int t = threadIdx.x;
  int v = (t < nb) ? bsums[t] : 0;
  sh[t] = v;
  __syncthreads();
  for (int off = 1; off < 256; off <<= 1) {
    int x = (t >= off) ? sh[t - off] : 0;
    __syncthreads();
    sh[t] += x;
    __syncthreads();
  }
  if (t < nb) bsums[t] = sh[t] - v;
}

__global__ void scatter_kernel(const int* __restrict__ ei, const int* __restrict__ flag,
                               int* __restrict__ offs, const int* __restrict__ bsums,
                               int2* __restrict__ sorted, int E) {
  const bool is64 = flag[0] != 0;
  int i = blockIdx.x * blockDim.x + threadIdx.x;
  const int st = gridDim.x * blockDim.x;
  for (; i < E; i += st) {
    int s = is64 ? ei[2 * i]         : ei[i];
    int d = is64 ? ei[2 * E + 2 * i] : ei[E + i];
    int p = atomicAdd(&offs[d], 1) + bsums[d >> 10];
    sorted[p] = make_int2(s, d);
  }
}

// ---------------- fused edge MLP (both layers MFMA) + segmented max ----------------
// 512 threads = 2 sub-blocks x (4 waves, one 64-edge tile). w2f shared in LDS.
// k-permutation: stored col kstore = m*8 + nt encodes true col c = 16*nt + m;
// w2 frags built with the same permutation on k, so h = u @ w2 is unchanged.

__global__ __launch_bounds__(512, 4) void edge_sorted_kernel(
    const float* __restrict__ x, const int2* __restrict__ sorted,
    const float* __restrict__ w1, const float* __restrict__ b1,
    const float* __restrict__ w2, const float* __restrict__ b2,
    float* agg, int N, int E) {
  __shared__ unsigned short us[2][EB * PADROW];   // uA then hS (bf16), per sub-block
  __shared__ short8 w2f[2048];                    // 32 frags x 64 lanes, k-permuted
  __shared__ int esS[2][EB], edS[2][EB];
  __shared__ int pnS[2][2];                       // dst before / after tile (-2 = none)
  __shared__ unsigned long long maskS[2];         // run-start bitmask

  const int t = threadIdx.x;
  const int sb = t >> 8;                          // sub-block (tile slot)
  const int tt = t & 255;
  const int lane = t & 63;
  const int w = tt >> 6;                          // wave within sub-block
  const int m = lane & 15;
  const int q = lane >> 4;

  // per-lane column biases (c = 16*nt + m)
  float b1c[8], b2c[8];
  #pragma unroll
  for (int nt = 0; nt < 8; ++nt) { b1c[nt] = b1[nt * 16 + m]; b2c[nt] = b2[nt * 16 + m]; }

  // layer-1 B frags in VGPRs: B1[k][n] = w1[k][n] for k<6 else 0
  short8 bf1[8];
  #pragma unroll
  for (int nt = 0; nt < 8; ++nt) {
    short8 v;
    #pragma unroll
    for (int j = 0; j < 8; ++j)
      v[j] = (q == 0 && j < 6) ? (short)f2bf(w1[j * NHID + nt * 16 + m]) : (short)0;
    bf1[nt] = v;
  }

  // layer-2 B frags in LDS, k-permuted
  for (int idx = t; idx < 2048; idx += 512) {
    const int fg = idx >> 6, ln = idx & 63;
    const int mm = ln & 15;
    const int kc = fg >> 3, nt = fg & 7;
    short8 v;
    #pragma unroll
    for (int j = 0; j < 8; ++j) {
      const int khw = kc * 32 + (ln >> 4) * 8 + j;
      const int ctrue = ((khw & 7) << 4) | (khw >> 3);
      v[j] = (short)f2bf(w2[ctrue * NHID + nt * 16 + mm]);
    }
    w2f[idx] = v;
  }

  const int jcol = tt & 127;                      // stage-3 stored column
  const int half = tt >> 7;                       // stage-3 row half
  const int ctr3 = ((jcol & 7) << 4) | (jcol >> 3);

  const int nbt = (E + EB - 1) / EB;
  const int npair = (nbt + 1) >> 1;
  __syncthreads();

  for (int bp = blockIdx.x; bp < npair; bp += gridDim.x) {
    const int tile = bp * 2 + sb;
    const int gbase = tile * EB;
    const bool live = (tile < nbt);

    if (tt < 64) {   // wave 0 of each sub-block: full 64-lane wave
      int d = -1, s = 0;
      int e = gbase + lane;
      if (live && e < E) { int2 v = sorted[e]; s = v.x; d = v.y; }
      esS[sb][lane] = s; edS[sb][lane] = d;
      int dprev = __shfl_up(d, 1);
      unsigned long long mk = __ballot(lane == 0 || d != dprev);
      if (lane == 0) {
        maskS[sb] = mk;
        pnS[sb][0] = (live && gbase > 0) ? sorted[gbase - 1].y : -2;
      }
      if (lane == 1)
        pnS[sb][1] = (live && gbase + EB < E) ? sorted[gbase + EB].y : -2;
    }
    __syncthreads();   // A: es/ed/mask/pn ready

    // ---- layer 1: u = relu(msg @ w1 + b1) via MFMA ----
    floatx4 acc[8];
    #pragma unroll
    for (int nt = 0; nt < 8; ++nt) { floatx4 z = {0.f, 0.f, 0.f, 0.f}; acc[nt] = z; }
    short8 a1 = {0, 0, 0, 0, 0, 0, 0, 0};
    if (q == 0) {
      const int e = 16 * w + m;
      const int si = esS[sb][e];
      const int d0 = edS[sb][e];
      const int di = (d0 < 0) ? 0 : d0;
      float xi0 = x[di * 3], xi1 = x[di * 3 + 1], xi2 = x[di * 3 + 2];
      float dd0 = x[si * 3] - xi0, dd1 = x[si * 3 + 1] - xi1, dd2 = x[si * 3 + 2] - xi2;
      union { short8 s; uint4 u; } cv;
      cv.u = make_uint4(pkbf(xi0, xi1), pkbf(xi2, dd0), pkbf(dd1, dd2), 0u);
      a1 = cv.s;
    }
    #pragma unroll
    for (int nt = 0; nt < 8; ++nt)
      acc[nt] = __builtin_amdgcn_mfma_f32_16x16x32_bf16(a1, bf1[nt], acc[nt], 0, 0, 0);

    // epilogue 1: relu(+b1) -> bf16, k-permuted rows (one b128 per row)
    #pragma unroll
    for (int r = 0; r < 4; ++r) {
      union { short8 s; uint4 u; } cv;
      cv.u = make_uint4(
        pkbf(fmaxf(acc[0][r] + b1c[0], 0.f), fmaxf(acc[1][r] + b1c[1], 0.f)),
        pkbf(fmaxf(acc[2][r] + b1c[2], 0.f), fmaxf(acc[3][r] + b1c[3], 0.f)),
        pkbf(fmaxf(acc[4][r] + b1c[4], 0.f), fmaxf(acc[5][r] + b1c[5], 0.f)),
        pkbf(fmaxf(acc[6][r] + b1c[6], 0.f), fmaxf(acc[7][r] + b1c[7], 0.f)));
      *(short8*)(&us[sb][(16 * w + q * 4 + r) * PADROW + m * 8]) = cv.s;
    }
    __syncthreads();   // B: uA ready

    // ---- layer 2: h = u @ w2 (k-permuted on both sides) ----
    #pragma unroll
    for (int nt = 0; nt < 8; ++nt) { floatx4 z = {0.f, 0.f, 0.f, 0.f}; acc[nt] = z; }
    #pragma unroll
    for (int kc = 0; kc < 4; ++kc) {
      short8 a = *(const short8*)(&us[sb][(16 * w + m) * PADROW + kc * 32 + q * 8]);
      #pragma unroll
      for (int nt = 0; nt < 8; ++nt)
        acc[nt] = __builtin_amdgcn_mfma_f32_16x16x32_bf16(a, w2f[(kc * 8 + nt) * 64 + lane],
                                                          acc[nt], 0, 0, 0);
    }
    __syncthreads();   // C: uA reads done

    // epilogue 2: clamp(h + b2, 0) -> bf16 hS (same layout, same buffer)
    #pragma unroll
    for (int r = 0; r < 4; ++r) {
      union { short8 s; uint4 u; } cv;
      cv.u = make_uint4(
        pkbf(fmaxf(acc[0][r] + b2c[0], 0.f), fmaxf(acc[1][r] + b2c[1], 0.f)),
        pkbf(fmaxf(acc[2][r] + b2c[2], 0.f), fmaxf(acc[3][r] + b2c[3], 0.f)),
        pkbf(fmaxf(acc[4][r] + b2c[4], 0.f), fmaxf(acc[5][r] + b2c[5], 0.f)),
        pkbf(fmaxf(acc[6][r] + b2c[6], 0.f), fmaxf(acc[7][r] + b2c[7], 0.f)));
      *(short8*)(&us[sb][(16 * w + q * 4 + r) * PADROW + m * 8]) = cv.s;
    }
    __syncthreads();   // D: hS ready

    // ---- stage 3: run-mask segmented max, u16 domain ----
    {
      const unsigned long long mk = maskS[sb];
      const int prevd = pnS[sb][0], nextd = pnS[sb][1];
      const int r0 = 32 * half, r1 = r0 + 32;
      // start of run containing r0 = highest set bit <= r0 (bit 0 always set)
      int s = 63 - __clzll(mk & (~0ULL >> (63 - r0)));
      while (s < r1) {
        const unsigned long long above = (s == 63) ? 0ULL : (mk & (~0ULL << (s + 1)));
        const int nxt = above ? (__ffsll((unsigned long long)above) - 1) : 64;
        const int d = edS[sb][s];
        if (d >= 0) {
          const int lo = (s > r0) ? s : r0;
          const int hi = (nxt < r1) ? nxt : r1;
          unsigned int run = 0;
          for (int r = lo; r < hi; ++r) {
            unsigned int vv = us[sb][r * PADROW + jcol];
            run = (run > vv) ? run : vv;
          }
          const int re = nxt - 1;
          const bool contained = (s >= r0) && (re < r1);
          const bool bnd = (s == 0 && prevd == d) || (re == 63 && nextd == d);
          const float v = __uint_as_float(run << 16);
          const size_t a = (size_t)d * NHID + ctr3;
          if (contained && !bnd) agg[a] = v;
          else atomicMax((unsigned int*)(agg + a), __float_as_uint(v));
        }
        s = nxt;
      }
    }
    __syncthreads();   // F: stage-3 reads done (protect es/ed/us)
  }
}

// ---------------- fallback: atomic edge kernel (small ws) ----------------

__global__ __launch_bounds__(256, 2) void edge_atomic_kernel(
    const float* __restrict__ x, const int* __restrict__ ei,
    const float* __restrict__ w1, const float* __restrict__ b1,
    const float* __restrict__ w2, const float* __restrict__ b2,
    float* agg, const int* __restrict__ flag64, int N, int E) {
  __shared__ unsigned short uA[EB * PADROW];
  __shared__ float w1s[6 * NHID];
  __shared__ float b1s[NHID], b2s[NHID];
  __shared__ int es[EB], ed[EB];

  const int t = threadIdx.x;
  const int lane = t & 63;
  const int w = t >> 6;
  const int m = lane & 15;
  const int q = lane >> 4;

  for (int i = t; i < 6 * NHID; i += 256) w1s[i] = w1[i];
  if (t < NHID) { b1s[t] = b1[t]; b2s[t] = b2[t]; }

  short8 bf[32];
  load_bfrags(w2, bf, m, q);

  const bool is64 = (flag64[0] != 0);
  const int nb = (E + EB - 1) / EB;

  for (int batch = blockIdx.x; batch < nb; batch += gridDim.x) {
    const int gbase = batch * EB;
    if (t < EB) {
      int e = gbase + t;
      es[t] = (e < E) ? (is64 ? ei[2 * e] : ei[e]) : 0;
    } else if (t < 2 * EB) {
      int tt = t - EB;
      int e = gbase + tt;
      ed[tt] = (e < E) ? (is64 ? ei[2 * E + 2 * e] : ei[E + e]) : 0;
    }
    __syncthreads();
    {
      const int e = t >> 2;
      const int c0 = (t & 3) * 32;
      const int si = es[e], di = ed[e];
      float xi0 = x[di * 3], xi1 = x[di * 3 + 1], xi2 = x[di * 3 + 2];
      float msg[6];
      msg[0] = xi0; msg[1] = xi1; msg[2] = xi2;
      msg[3] = x[si * 3] - xi0; msg[4] = x[si * 3 + 1] - xi1; msg[5] = x[si * 3 + 2] - xi2;
      unsigned int* d32 = (unsigned int*)uA;
      const int base32 = (e * PADROW + c0) >> 1;
      #pragma unroll
      for (int cc = 0; cc < 32; cc += 2) {
        float u0 = b1s[c0 + cc], u1 = b1s[c0 + cc + 1];
        #pragma unroll
        for (int d = 0; d < 6; ++d) {
          u0 += msg[d] * w1s[d * NHID + c0 + cc];
          u1 += msg[d] * w1s[d * NHID + c0 + cc + 1];
        }
        d32[base32 + (cc >> 1)] = pack2(fmaxf(u0, 0.f), fmaxf(u1, 0.f));
      }
    }
    __syncthreads();

    floatx4 acc[8];
    #pragma unroll
    for (int nt = 0; nt < 8; ++nt) { floatx4 z = {0.f, 0.f, 0.f, 0.f}; acc[nt] = z; }
    mfma_block(uA, bf, acc, w, m, q);

    #pragma unroll
    for (int nt = 0; nt < 8; ++nt) {
      const int c = nt * 16 + m;
      const float bb = b2s[c];
      #pragma unroll
      for (int r = 0; r < 4; ++r) {
        const int erow = 16 * w + q * 4 + r;
        if (gbase + erow < E) {
          float hb = acc[nt][r] + bb;
          if (hb > 0.f)
            atomicMax((unsigned int*)(agg + (size_t)ed[erow] * NHID + c),
                      __float_as_uint(hb));
        }
      }
    }
    __syncthreads();
  }
}

// ---------------- node MLPs ----------------

__global__ __launch_bounds__(256, 2) void enc_kernel(
    const float* __restrict__ w3, const float* __restrict__ b3,
    float* agg, int N) {
  __shared__ unsigned short uA[EB * PADROW];
  __shared__ float b3s[NHID];

  const int t = threadIdx.x;
  const int lane = t & 63;
  const int w = t >> 6;
  const int m = lane & 15;
  const int q = lane >> 4;

  if (t < NHID) b3s[t] = b3[t];
  short8 bf[32];
  load_bfrags(w3, bf, m, q);

  const int nb = (N + EB - 1) / EB;
  for (int batch = blockIdx.x; batch < nb; batch += gridDim.x) {
    const int base = batch * EB;
    __syncthreads();
    for (int i = t; i < EB * 32; i += 256) {
      const int row = i >> 5, c4 = i & 31;
      const int node = base + row;
      float4 v = make_float4(0.f, 0.f, 0.f, 0.f);
      if (node < N) v = ((const float4*)agg)[(size_t)node * 32 + c4];
      unsigned int* d32 = (unsigned int*)uA;
      const int o = row * (PADROW >> 1) + c4 * 2;
      d32[o] = pack2(v.x, v.y);
      d32[o + 1] = pack2(v.z, v.w);
    }
    __syncthreads();

    floatx4 acc[8];
    #pragma unroll
    for (int nt = 0; nt < 8; ++nt) { floatx4 z = {0.f, 0.f, 0.f, 0.f}; acc[nt] = z; }
    mfma_block(uA, bf, acc, w, m, q);

    #pragma unroll
    for (int nt = 0; nt < 8; ++nt) {
      const int c = nt * 16 + m;
      const float bb = b3s[c];
      #pragma unroll
      for (int r = 0; r < 4; ++r) {
        const int node = base + 16 * w + q * 4 + r;
        if (node < N) agg[(size_t)node * NHID + c] = acc[nt][r] + bb;
      }
    }
  }
}

__global__ __launch_bounds__(256, 2) void dec_kernel(
    const float* __restrict__ w4, const float* __restrict__ b4,
    const float* __restrict__ w5, const float* __restrict__ b5,
    const float* __restrict__ pos, const float* __restrict__ enc,
    float* __restrict__ out, int N) {
  __shared__ unsigned short uA[EB * PADROW];
  __shared__ float b4s[NHID];
  __shared__ float w5s[NHID * 3];

  const int t = threadIdx.x;
  const int lane = t & 63;
  const int w = t >> 6;
  const int m = lane & 15;
  const int q = lane >> 4;

  if (t < NHID) b4s[t] = b4[t];
  for (int i = t; i < NHID * 3; i += 256) w5s[i] = w5[i];
  short8 bf[32];
  load_bfrags(w4, bf, m, q);

  const int nb = (N + EB - 1) / EB;
  for (int batch = blockIdx.x; batch < nb; batch += gridDim.x) {
    const int base = batch * EB;
    __syncthreads();
    for (int i = t; i < EB * 32; i += 256) {
      const int row = i >> 5, c4 = i & 31;
      const int node = base + row;
      float4 v = make_float4(0.f, 0.f, 0.f, 0.f);
      if (node < N) v = ((const float4*)enc)[(size_t)node * 32 + c4];
      unsigned int* d32 = (unsigned int*)uA;
      const int o = row * (PADROW >> 1) + c4 * 2;
      d32[o] = pack2(v.x, v.y);
      d32[o + 1] = pack2(v.z, v.w);
    }
    __syncthreads();

    floatx4 acc[8];
    #pragma unroll
    for (int nt = 0; nt < 8; ++nt) { floatx4 z = {0.f, 0.f, 0.f, 0.f}; acc[nt] = z; }
    mfma_block(uA, bf, acc, w, m, q);

    float p[4][3];
    #pragma unroll
    for (int r = 0; r < 4; ++r) { p[r][0] = 0.f; p[r][1] = 0.f; p[r][2] = 0.f; }
    #pragma unroll
    for (int nt = 0; nt < 8; ++nt) {
      const int c = nt * 16 + m;
      const float bb = b4s[c];
      const float w50 = w5s[c * 3], w51 = w5s[c * 3 + 1], w52 = w5s[c * 3 + 2];
      #pragma unroll
      for (int r = 0; r < 4; ++r) {
        float tv = fmaxf(acc[nt][r] + bb, 0.f);
        p[r][0] += tv * w50; p[r][1] += tv * w51; p[r][2] += tv * w52;
      }
    }
    #pragma unroll
    for (int off = 8; off >= 1; off >>= 1) {
      #pragma unroll
      for (int r = 0; r < 4; ++r) {
        p[r][0] += __shfl_xor(p[r][0], off, 16);
        p[r][1] += __shfl_xor(p[r][1], off, 16);
        p[r][2] += __shfl_xor(p[r][2], off, 16);
      }
    }
    if (m == 0) {
      #pragma unroll
      for (int r = 0; r < 4; ++r) {
        const int node = base + 16 * w + q * 4 + r;
        if (node < N) {
          #pragma unroll
          for (int j = 0; j < 3; ++j) {
            float dec = p[r][j] + b5[j];
            out[node * 3 + j] = pos[node * 3 + j] + 0.1f * tanhf(dec);
          }
        }
      }
    }
  }
}

extern "C" void kernel_launch(void* const* d_in, const int* in_sizes, int n_in,
                              void* d_out, int out_size, void* d_ws, size_t ws_size,
                              hipStream_t stream) {
  const float* x   = (const float*)d_in[0];
  const float* pos = (const float*)d_in[1];
  const int*   ei  = (const int*)d_in[2];
  const float* w1  = (const float*)d_in[3];
  const float* b1  = (const float*)d_in[4];
  const float* w2  = (const float*)d_in[5];
  const float* b2  = (const float*)d_in[6];
  const float* w3  = (const float*)d_in[7];
  const float* b3  = (const float*)d_in[8];
  const float* w4  = (const float*)d_in[9];
  const float* b4  = (const float*)d_in[10];
  const float* w5  = (const float*)d_in[11];
  const float* b5  = (const float*)d_in[12];
  float* out = (float*)d_out;

  const int N = in_sizes[0] / 3;
  const int E = in_sizes[2] / 2;

  char* ws = (char*)d_ws;
  float* agg = (float*)ws;                                    // N*128 f32
  const size_t aggBytes = (size_t)N * NHID * sizeof(float);
  int*  cnt    = (int*)(ws + aggBytes);                       // N ints
  int2* sorted = (int2*)(ws + aggBytes + (size_t)N * 4);      // E int2
  int*  bsums  = (int*)(ws + aggBytes + (size_t)N * 4 + (size_t)E * 8);
  int*  flag   = bsums + 1024;
  const size_t needed = aggBytes + (size_t)N * 4 + (size_t)E * 8 + 1024 * 4 + 16;
  const int nbA = (N + 1023) / 1024;

  if (ws_size >= needed && nbA <= 256) {
    zero_detect_kernel<<<2048, 256, 0, stream>>>((float4*)agg, (N * 129 + 3) / 4, ei, flag);
    hist_kernel<<<2048, 256, 0, stream>>>(ei, flag, cnt, E);
    scan_a<<<nbA, 256, 0, stream>>>(cnt, bsums, N);
    scan_b<<<1, 256, 0, stream>>>(bsums, nbA);
    scatter_kernel<<<2048, 256, 0, stream>>>(ei, flag, cnt, bsums, sorted, E);
    edge_sorted_kernel<<<512, 512, 0, stream>>>(x, sorted, w1, b1, w2, b2, agg, N, E);
  } else {
    int* flag2 = (int*)(ws + aggBytes);
    zero_detect_kernel<<<2048, 256, 0, stream>>>((float4*)agg, N * NHID / 4, ei, flag2);
    edge_atomic_kernel<<<512, 256, 0, stream>>>(x, ei, w1, b1, w2, b2, agg, flag2, N, E);
  }
  enc_kernel<<<512, 256, 0, stream>>>(w3, b3, agg, N);
  dec_kernel<<<512, 256, 0, stream>>>(w4, b4, w5, b5, pos, agg, out, N);
}

// Round 5
// 498.508 us; speedup vs baseline: 1.5807x; 1.0587x over previous
//
#include <hip/hip_runtime.h>
#include <hip/hip_bf16.h>

typedef __attribute__((ext_vector_type(8))) short short8;
typedef __attribute__((ext_vector_type(4))) float floatx4;
typedef __attribute__((ext_vector_type(2))) unsigned short ushortx2;

#define NHID 128
#define PADROW 136   // u16 row stride: 272B, 16B-aligned b128, benign banking
#define EB 64        // edges (or nodes) per tile

__device__ __forceinline__ unsigned short f2bf(float x) {
  unsigned int u = __float_as_uint(x);
  u += 0x7FFFu + ((u >> 16) & 1u);          // RNE
  return (unsigned short)(u >> 16);
}

__device__ __forceinline__ unsigned int pkbf(float a, float b) {
  __hip_bfloat162 h = __float22bfloat162_rn(make_float2(a, b));
  union { __hip_bfloat162 h; unsigned int u; } cv;
  cv.h = h;
  return cv.u;
}

__device__ __forceinline__ unsigned int pack2(float a, float b) {
  return (unsigned int)f2bf(a) | ((unsigned int)f2bf(b) << 16);
}

// packed u16 max (v_pk_max_u16)
__device__ __forceinline__ unsigned int pkmax(unsigned int a, unsigned int b) {
  union { unsigned int u; ushortx2 v; } x, y;
  x.u = a; y.u = b;
  x.v = __builtin_elementwise_max(x.v, y.v);
  return x.u;
}

// 32 loop-invariant B-fragments of a 128x128 row-major f32 weight (registers).
__device__ __forceinline__ void load_bfrags(const float* __restrict__ wmat,
                                            short8* bf, int m, int q) {
  #pragma unroll
  for (int kc = 0; kc < 4; ++kc) {
    #pragma unroll
    for (int nt = 0; nt < 8; ++nt) {
      short8 v;
      #pragma unroll
      for (int j = 0; j < 8; ++j)
        v[j] = (short)f2bf(wmat[(kc * 32 + q * 8 + j) * NHID + nt * 16 + m]);
      bf[kc * 8 + nt] = v;
    }
  }
}

__device__ __forceinline__ void mfma_block(const unsigned short* uA,
                                           const short8* bf, floatx4* acc,
                                           int w, int m, int q) {
  #pragma unroll
  for (int kc = 0; kc < 4; ++kc) {
    short8 a = *(const short8*)(uA + (16 * w + m) * PADROW + kc * 32 + q * 8);
    #pragma unroll
    for (int nt = 0; nt < 8; ++nt)
      acc[nt] = __builtin_amdgcn_mfma_f32_16x16x32_bf16(a, bf[kc * 8 + nt],
                                                        acc[nt], 0, 0, 0);
  }
}

// zero cnt; block 0 also runs the int64-vs-int32 edge_index probe.
__global__ void zero_cnt_detect_kernel(int* __restrict__ cnt, int N,
                                       const int* __restrict__ ei, int* __restrict__ flag) {
  if (blockIdx.x == 0 && threadIdx.x < 64) {
    unsigned long long b = __ballot(ei[2 * threadIdx.x + 1] != 0);
    if (threadIdx.x == 0) flag[0] = (b == 0ULL) ? 1 : 0;
  }
  int i = blockIdx.x * blockDim.x + threadIdx.x;
  const int st = gridDim.x * blockDim.x;
  for (; i < N; i += st) cnt[i] = 0;
}

// fallback-path zero (agg) + detect
__global__ void zero_detect_kernel(float4* __restrict__ p, int n4,
                                   const int* __restrict__ ei, int* __restrict__ flag) {
  if (blockIdx.x == 0 && threadIdx.x < 64) {
    unsigned long long b = __ballot(ei[2 * threadIdx.x + 1] != 0);
    if (threadIdx.x == 0) flag[0] = (b == 0ULL) ? 1 : 0;
  }
  int i = blockIdx.x * blockDim.x + threadIdx.x;
  int stride = gridDim.x * blockDim.x;
  float4 z = make_float4(0.f, 0.f, 0.f, 0.f);
  for (; i < n4; i += stride) p[i] = z;
}

// ---------------- counting sort by dst ----------------

#define HISTB 1536   // blocks doing histogram; the rest memset agg

__global__ void hist_zero_kernel(const int* __restrict__ ei, const int* __restrict__ flag,
                                 int* __restrict__ cnt, int E,
                                 float4* __restrict__ aggz, int n4) {
  if (blockIdx.x < HISTB) {
    const bool is64 = flag[0] != 0;
    int i = blockIdx.x * blockDim.x + threadIdx.x;
    const int st = HISTB * blockDim.x;
    for (; i < E; i += st) {
      int d = is64 ? ei[2 * E + 2 * i] : ei[E + i];
      atomicAdd(&cnt[d], 1);
    }
  } else {
    int i = (blockIdx.x - HISTB) * blockDim.x + threadIdx.x;
    const int st = (gridDim.x - HISTB) * blockDim.x;
    float4 z = make_float4(0.f, 0.f, 0.f, 0.f);
    for (; i < n4; i += st) aggz[i] = z;
  }
}

__global__ void scan_a(int* __restrict__ cnt, int* __restrict__ bsums, int N) {
  __shared__ int sh[256];
  const int t = threadIdx.x;
  const int base = blockIdx.x * 1024 + t * 4;
  int v0 = (base     < N) ? cnt[base]     : 0;
  int v1 = (base + 1 < N) ? cnt[base + 1] : 0;
  int v2 = (base + 2 < N) ? cnt[base + 2] : 0;
  int v3 = (base + 3 < N) ? cnt[base + 3] : 0;
  sh[t] = v0 + v1 + v2 + v3;
  __syncthreads();
  for (int off = 1; off < 256; off <<= 1) {
    int x = (t >= off) ? sh[t - off] : 0;
    __syncthreads();
    sh[t] += x;
    __syncthreads();
  }
  int excl = (t > 0) ? sh[t - 1] : 0;
  if (base     < N) cnt[base]     = excl;
  if (base + 1 < N) cnt[base + 1] = excl + v0;
  if (base + 2 < N) cnt[base + 2] = excl + v0 + v1;
  if (base + 3 < N) cnt[base + 3] = excl + v0 + v1 + v2;
  if (t == 0) bsums[blockIdx.x] = sh[255];
}

__global__ void scan_b(int* __restrict__ bsums, int nb) {
  __shared__ int sh[256];
  const int t = threadIdx.x;
  int v = (t < nb) ? bsums[t] : 0;
  sh[t] = v;
  __syncthreads();
  for (int off = 1; off < 256; off <<= 1) {
    int x = (t >= off) ? sh[t - off] : 0;
    __syncthreads();
    sh[t] += x;
    __syncthreads();
  }
  if (t < nb) bsums[t] = sh[t] - v;
}

__global__ void scatter_kernel(const int* __restrict__ ei, const int* __restrict__ flag,
                               int* __restrict__ offs, const int* __restrict__ bsums,
                               int2* __restrict__ sorted, int E) {
  const bool is64 = flag[0] != 0;
  int i = blockIdx.x * blockDim.x + threadIdx.x;
  const int st = gridDim.x * blockDim.x;
  for (; i < E; i += st) {
    int s = is64 ? ei[2 * i]         : ei[i];
    int d = is64 ? ei[2 * E + 2 * i] : ei[E + i];
    int p = atomicAdd(&offs[d], 1) + bsums[d >> 10];
    sorted[p] = make_int2(s, d);
  }
}

// ---------------- fused edge MLP (both layers MFMA) + segmented max ----------------
// 512 threads = 2 sub-blocks x (4 waves, one 64-edge tile). w2f shared in LDS.
// k-permutation: stored col kstore = m*8 + nt encodes true col c = 16*nt + m;
// w2 frags built with the same permutation on k, so h = u @ w2 is unchanged.

__global__ __launch_bounds__(512, 4) void edge_sorted_kernel(
    const float* __restrict__ x, const int2* __restrict__ sorted,
    const float* __restrict__ w1, const float* __restrict__ b1,
    const float* __restrict__ w2, const float* __restrict__ b2,
    float* agg, int N, int E) {
  __shared__ unsigned short us[2][EB * PADROW];   // uA then hS (bf16), per sub-block
  __shared__ short8 w2f[2048];                    // 32 frags x 64 lanes, k-permuted
  __shared__ int esS[2][EB], edS[2][EB];
  __shared__ int pnS[2][2];                       // dst before / after tile (-2 = none)
  __shared__ unsigned long long maskS[2];         // run-start bitmask

  const int t = threadIdx.x;
  const int sb = t >> 8;                          // sub-block (tile slot)
  const int tt = t & 255;
  const int lane = t & 63;
  const int w = tt >> 6;                          // wave within sub-block
  const int m = lane & 15;
  const int q = lane >> 4;

  // per-lane column biases (c = 16*nt + m)
  float b1c[8], b2c[8];
  #pragma unroll
  for (int nt = 0; nt < 8; ++nt) { b1c[nt] = b1[nt * 16 + m]; b2c[nt] = b2[nt * 16 + m]; }

  // layer-1 B frags in VGPRs: B1[k][n] = w1[k][n] for k<6 else 0
  short8 bf1[8];
  #pragma unroll
  for (int nt = 0; nt < 8; ++nt) {
    short8 v;
    #pragma unroll
    for (int j = 0; j < 8; ++j)
      v[j] = (q == 0 && j < 6) ? (short)f2bf(w1[j * NHID + nt * 16 + m]) : (short)0;
    bf1[nt] = v;
  }

  // layer-2 B frags in LDS, k-permuted
  for (int idx = t; idx < 2048; idx += 512) {
    const int fg = idx >> 6, ln = idx & 63;
    const int mm = ln & 15;
    const int kc = fg >> 3, nt = fg & 7;
    short8 v;
    #pragma unroll
    for (int j = 0; j < 8; ++j) {
      const int khw = kc * 32 + (ln >> 4) * 8 + j;
      const int ctrue = ((khw & 7) << 4) | (khw >> 3);
      v[j] = (short)f2bf(w2[ctrue * NHID + nt * 16 + mm]);
    }
    w2f[idx] = v;
  }

  // stage-3 thread mapping: 4 row-quarters x 64 u32-cols
  const int jc = tt & 63;
  const int quarter = tt >> 6;
  const int c_lo = 32 * (jc & 3) + (jc >> 2);     // true col of lo16
  const int c_hi = c_lo + 16;                     // true col of hi16

  const int nbt = (E + EB - 1) / EB;
  const int npair = (nbt + 1) >> 1;
  __syncthreads();

  for (int bp = blockIdx.x; bp < npair; bp += gridDim.x) {
    const int tile = bp * 2 + sb;
    const int gbase = tile * EB;
    const bool live = (tile < nbt);

    if (tt < 64) {   // wave 0 of each sub-block: full 64-lane wave
      int d = -1, s = 0;
      int e = gbase + lane;
      if (live && e < E) { int2 v = sorted[e]; s = v.x; d = v.y; }
      esS[sb][lane] = s; edS[sb][lane] = d;
      int dprev = __shfl_up(d, 1);
      unsigned long long mk = __ballot(lane == 0 || d != dprev);
      if (lane == 0) {
        maskS[sb] = mk;
        pnS[sb][0] = (live && gbase > 0) ? sorted[gbase - 1].y : -2;
      }
      if (lane == 1)
        pnS[sb][1] = (live && gbase + EB < E) ? sorted[gbase + EB].y : -2;
    }
    __syncthreads();   // A: es/ed/mask/pn ready

    // ---- layer 1: u = relu(msg @ w1 + b1) via MFMA ----
    floatx4 acc[8];
    #pragma unroll
    for (int nt = 0; nt < 8; ++nt) { floatx4 z = {0.f, 0.f, 0.f, 0.f}; acc[nt] = z; }
    short8 a1 = {0, 0, 0, 0, 0, 0, 0, 0};
    if (q == 0) {
      const int e = 16 * w + m;
      const int si = esS[sb][e];
      const int d0 = edS[sb][e];
      const int di = (d0 < 0) ? 0 : d0;
      float xi0 = x[di * 3], xi1 = x[di * 3 + 1], xi2 = x[di * 3 + 2];
      float dd0 = x[si * 3] - xi0, dd1 = x[si * 3 + 1] - xi1, dd2 = x[si * 3 + 2] - xi2;
      union { short8 s; uint4 u; } cv;
      cv.u = make_uint4(pkbf(xi0, xi1), pkbf(xi2, dd0), pkbf(dd1, dd2), 0u);
      a1 = cv.s;
    }
    #pragma unroll
    for (int nt = 0; nt < 8; ++nt)
      acc[nt] = __builtin_amdgcn_mfma_f32_16x16x32_bf16(a1, bf1[nt], acc[nt], 0, 0, 0);

    // epilogue 1: relu(+b1) -> bf16, k-permuted rows (one b128 per row)
    #pragma unroll
    for (int r = 0; r < 4; ++r) {
      union { short8 s; uint4 u; } cv;
      cv.u = make_uint4(
        pkbf(fmaxf(acc[0][r] + b1c[0], 0.f), fmaxf(acc[1][r] + b1c[1], 0.f)),
        pkbf(fmaxf(acc[2][r] + b1c[2], 0.f), fmaxf(acc[3][r] + b1c[3], 0.f)),
        pkbf(fmaxf(acc[4][r] + b1c[4], 0.f), fmaxf(acc[5][r] + b1c[5], 0.f)),
        pkbf(fmaxf(acc[6][r] + b1c[6], 0.f), fmaxf(acc[7][r] + b1c[7], 0.f)));
      *(short8*)(&us[sb][(16 * w + q * 4 + r) * PADROW + m * 8]) = cv.s;
    }
    __syncthreads();   // B: uA ready

    // ---- layer 2: h = u @ w2 (k-permuted on both sides) ----
    #pragma unroll
    for (int nt = 0; nt < 8; ++nt) { floatx4 z = {0.f, 0.f, 0.f, 0.f}; acc[nt] = z; }
    #pragma unroll
    for (int kc = 0; kc < 4; ++kc) {
      short8 a = *(const short8*)(&us[sb][(16 * w + m) * PADROW + kc * 32 + q * 8]);
      #pragma unroll
      for (int nt = 0; nt < 8; ++nt)
        acc[nt] = __builtin_amdgcn_mfma_f32_16x16x32_bf16(a, w2f[(kc * 8 + nt) * 64 + lane],
                                                          acc[nt], 0, 0, 0);
    }
    __syncthreads();   // C: uA reads done

    // epilogue 2: clamp(h + b2, 0) -> bf16 hS (same layout, same buffer)
    #pragma unroll
    for (int r = 0; r < 4; ++r) {
      union { short8 s; uint4 u; } cv;
      cv.u = make_uint4(
        pkbf(fmaxf(acc[0][r] + b2c[0], 0.f), fmaxf(acc[1][r] + b2c[1], 0.f)),
        pkbf(fmaxf(acc[2][r] + b2c[2], 0.f), fmaxf(acc[3][r] + b2c[3], 0.f)),
        pkbf(fmaxf(acc[4][r] + b2c[4], 0.f), fmaxf(acc[5][r] + b2c[5], 0.f)),
        pkbf(fmaxf(acc[6][r] + b2c[6], 0.f), fmaxf(acc[7][r] + b2c[7], 0.f)));
      *(short8*)(&us[sb][(16 * w + q * 4 + r) * PADROW + m * 8]) = cv.s;
    }
    __syncthreads();   // D: hS ready

    // ---- stage 3: packed segmented max (u16 pairs), 4 quarters x 64 u32-cols ----
    {
      const unsigned long long mk = maskS[sb];
      const int prevd = pnS[sb][0], nextd = pnS[sb][1];
      const int r0 = quarter * 16, r1 = r0 + 16;
      const unsigned int* us32 = (const unsigned int*)&us[sb][0];
      int s = 63 - __clzll(mk & (~0ULL >> (63 - r0)));
      while (s < r1) {
        const unsigned long long above = (s == 63) ? 0ULL : (mk & (~0ULL << (s + 1)));
        const int nxt = above ? (__ffsll((unsigned long long)above) - 1) : 64;
        const int d = edS[sb][s];
        if (d >= 0) {
          const int lo = (s > r0) ? s : r0;
          const int hi = (nxt < r1) ? nxt : r1;
          unsigned int run = 0;
          for (int r = lo; r < hi; ++r)
            run = pkmax(run, us32[r * (PADROW >> 1) + jc]);
          const bool contained = (s >= r0) && (nxt <= r1);
          const bool bnd = (s == 0 && prevd == d) || (nxt == 64 && nextd == d);
          const unsigned int vlo = run & 0xFFFFu, vhi = run >> 16;
          const size_t alo = (size_t)d * NHID + c_lo;
          const size_t ahi = (size_t)d * NHID + c_hi;
          if (contained && !bnd) {
            agg[alo] = __uint_as_float(vlo << 16);
            agg[ahi] = __uint_as_float(vhi << 16);
          } else {
            if (vlo) atomicMax((unsigned int*)(agg + alo), vlo << 16);
            if (vhi) atomicMax((unsigned int*)(agg + ahi), vhi << 16);
          }
        }
        s = nxt;
      }
    }
    __syncthreads();   // F: stage-3 reads done (protect es/ed/us)
  }
}

// ---------------- fallback: atomic edge kernel (small ws) ----------------

__global__ __launch_bounds__(256, 2) void edge_atomic_kernel(
    const float* __restrict__ x, const int* __restrict__ ei,
    const float* __restrict__ w1, const float* __restrict__ b1,
    const float* __restrict__ w2, const float* __restrict__ b2,
    float* agg, const int* __restrict__ flag64, int N, int E) {
  __shared__ unsigned short uA[EB * PADROW];
  __shared__ float w1s[6 * NHID];
  __shared__ float b1s[NHID], b2s[NHID];
  __shared__ int es[EB], ed[EB];

  const int t = threadIdx.x;
  const int lane = t & 63;
  const int w = t >> 6;
  const int m = lane & 15;
  const int q = lane >> 4;

  for (int i = t; i < 6 * NHID; i += 256) w1s[i] = w1[i];
  if (t < NHID) { b1s[t] = b1[t]; b2s[t] = b2[t]; }

  short8 bf[32];
  load_bfrags(w2, bf, m, q);

  const bool is64 = (flag64[0] != 0);
  const int nb = (E + EB - 1) / EB;

  for (int batch = blockIdx.x; batch < nb; batch += gridDim.x) {
    const int gbase = batch * EB;
    if (t < EB) {
      int e = gbase + t;
      es[t] = (e < E) ? (is64 ? ei[2 * e] : ei[e]) : 0;
    } else if (t < 2 * EB) {
      int tt = t - EB;
      int e = gbase + tt;
      ed[tt] = (e < E) ? (is64 ? ei[2 * E + 2 * e] : ei[E + e]) : 0;
    }
    __syncthreads();
    {
      const int e = t >> 2;
      const int c0 = (t & 3) * 32;
      const int si = es[e], di = ed[e];
      float xi0 = x[di * 3], xi1 = x[di * 3 + 1], xi2 = x[di * 3 + 2];
      float msg[6];
      msg[0] = xi0; msg[1] = xi1; msg[2] = xi2;
      msg[3] = x[si * 3] - xi0; msg[4] = x[si * 3 + 1] - xi1; msg[5] = x[si * 3 + 2] - xi2;
      unsigned int* d32 = (unsigned int*)uA;
      const int base32 = (e * PADROW + c0) >> 1;
      #pragma unroll
      for (int cc = 0; cc < 32; cc += 2) {
        float u0 = b1s[c0 + cc], u1 = b1s[c0 + cc + 1];
        #pragma unroll
        for (int d = 0; d < 6; ++d) {
          u0 += msg[d] * w1s[d * NHID + c0 + cc];
          u1 += msg[d] * w1s[d * NHID + c0 + cc + 1];
        }
        d32[base32 + (cc >> 1)] = pack2(fmaxf(u0, 0.f), fmaxf(u1, 0.f));
      }
    }
    __syncthreads();

    floatx4 acc[8];
    #pragma unroll
    for (int nt = 0; nt < 8; ++nt) { floatx4 z = {0.f, 0.f, 0.f, 0.f}; acc[nt] = z; }
    mfma_block(uA, bf, acc, w, m, q);

    #pragma unroll
    for (int nt = 0; nt < 8; ++nt) {
      const int c = nt * 16 + m;
      const float bb = b2s[c];
      #pragma unroll
      for (int r = 0; r < 4; ++r) {
        const int erow = 16 * w + q * 4 + r;
        if (gbase + erow < E) {
          float hb = acc[nt][r] + bb;
          if (hb > 0.f)
            atomicMax((unsigned int*)(agg + (size_t)ed[erow] * NHID + c),
                      __float_as_uint(hb));
        }
      }
    }
    __syncthreads();
  }
}

// ---------------- fused node MLPs: enc (w3) + dec (w4,w5) ----------------

__global__ __launch_bounds__(256, 2) void encdec_kernel(
    const float* __restrict__ w3, const float* __restrict__ b3,
    const float* __restrict__ w4, const float* __restrict__ b4,
    const float* __restrict__ w5, const float* __restrict__ b5,
    const float* __restrict__ pos, const float* __restrict__ agg,
    float* __restrict__ out, int N) {
  __shared__ unsigned short uA[EB * PADROW];
  __shared__ short8 w4f[2048];                    // k-permuted w4 frags
  __shared__ float w5s[NHID * 3];

  const int t = threadIdx.x;
  const int lane = t & 63;
  const int w = t >> 6;
  const int m = lane & 15;
  const int q = lane >> 4;

  float b3c[8], b4c[8];
  #pragma unroll
  for (int nt = 0; nt < 8; ++nt) { b3c[nt] = b3[nt * 16 + m]; b4c[nt] = b4[nt * 16 + m]; }

  short8 bf3[32];
  load_bfrags(w3, bf3, m, q);                     // natural layout (uA natural for L1)

  for (int idx = t; idx < 2048; idx += 256) {
    const int fg = idx >> 6, ln = idx & 63;
    const int mm = ln & 15;
    const int kc = fg >> 3, nt = fg & 7;
    short8 v;
    #pragma unroll
    for (int j = 0; j < 8; ++j) {
      const int khw = kc * 32 + (ln >> 4) * 8 + j;
      const int ctrue = ((khw & 7) << 4) | (khw >> 3);
      v[j] = (short)f2bf(w4[ctrue * NHID + nt * 16 + mm]);
    }
    w4f[idx] = v;
  }
  for (int i = t; i < NHID * 3; i += 256) w5s[i] = w5[i];
  const float b50 = b5[0], b51 = b5[1], b52 = b5[2];

  const int nb = (N + EB - 1) / EB;
  __syncthreads();

  for (int batch = blockIdx.x; batch < nb; batch += gridDim.x) {
    const int base = batch * EB;
    // stage 0: agg tile -> bf16 uA (natural layout)
    for (int i = t; i < EB * 32; i += 256) {
      const int row = i >> 5, c4 = i & 31;
      const int node = base + row;
      float4 v = make_float4(0.f, 0.f, 0.f, 0.f);
      if (node < N) v = ((const float4*)agg)[(size_t)node * 32 + c4];
      unsigned int* d32 = (unsigned int*)uA;
      const int o = row * (PADROW >> 1) + c4 * 2;
      d32[o] = pkbf(v.x, v.y);
      d32[o + 1] = pkbf(v.z, v.w);
    }
    __syncthreads();   // B0: uA ready

    floatx4 acc[8];
    #pragma unroll
    for (int nt = 0; nt < 8; ++nt) { floatx4 z = {0.f, 0.f, 0.f, 0.f}; acc[nt] = z; }
    mfma_block(uA, bf3, acc, w, m, q);
    __syncthreads();   // B1: uA reads done

    // E1: enc = acc + b3 -> bf16, k-permuted rows (NOT clamped — enc can be <0)
    #pragma unroll
    for (int r = 0; r < 4; ++r) {
      union { short8 s; uint4 u; } cv;
      cv.u = make_uint4(
        pkbf(acc[0][r] + b3c[0], acc[1][r] + b3c[1]),
        pkbf(acc[2][r] + b3c[2], acc[3][r] + b3c[3]),
        pkbf(acc[4][r] + b3c[4], acc[5][r] + b3c[5]),
        pkbf(acc[6][r] + b3c[6], acc[7][r] + b3c[7]));
      *(short8*)(&uA[(16 * w + q * 4 + r) * PADROW + m * 8]) = cv.s;
    }
    __syncthreads();   // B2: enc ready

    // L2: th = enc @ w4 (k-permuted both sides)
    #pragma unroll
    for (int nt = 0; nt < 8; ++nt) { floatx4 z = {0.f, 0.f, 0.f, 0.f}; acc[nt] = z; }
    #pragma unroll
    for (int kc = 0; kc < 4; ++kc) {
      short8 a = *(const short8*)(&uA[(16 * w + m) * PADROW + kc * 32 + q * 8]);
      #pragma unroll
      for (int nt = 0; nt < 8; ++nt)
        acc[nt] = __builtin_amdgcn_mfma_f32_16x16x32_bf16(a, w4f[(kc * 8 + nt) * 64 + lane],
                                                          acc[nt], 0, 0, 0);
    }

    // E2: tv = relu(th + b4); dec = tv @ w5 + b5; out = pos + 0.1*tanh(dec)
    float p[4][3];
    #pragma unroll
    for (int r = 0; r < 4; ++r) { p[r][0] = 0.f; p[r][1] = 0.f; p[r][2] = 0.f; }
    #pragma unroll
    for (int nt = 0; nt < 8; ++nt) {
      const int c = nt * 16 + m;
      const float bb = b4c[nt];
      const float w50 = w5s[c * 3], w51 = w5s[c * 3 + 1], w52 = w5s[c * 3 + 2];
      #pragma unroll
      for (int r = 0; r < 4; ++r) {
        float tv = fmaxf(acc[nt][r] + bb, 0.f);
        p[r][0] += tv * w50; p[r][1] += tv * w51; p[r][2] += tv * w52;
      }
    }
    #pragma unroll
    for (int off = 8; off >= 1; off >>= 1) {
      #pragma unroll
      for (int r = 0; r < 4; ++r) {
        p[r][0] += __shfl_xor(p[r][0], off, 16);
        p[r][1] += __shfl_xor(p[r][1], off, 16);
        p[r][2] += __shfl_xor(p[r][2], off, 16);
      }
    }
    if (m == 0) {
      #pragma unroll
      for (int r = 0; r < 4; ++r) {
        const int node = base + 16 * w + q * 4 + r;
        if (node < N) {
          out[node * 3]     = pos[node * 3]     + 0.1f * tanhf(p[r][0] + b50);
          out[node * 3 + 1] = pos[node * 3 + 1] + 0.1f * tanhf(p[r][1] + b51);
          out[node * 3 + 2] = pos[node * 3 + 2] + 0.1f * tanhf(p[r][2] + b52);
        }
      }
    }
    __syncthreads();   // B3: L2 reads done (protect uA for next stage 0)
  }
}

extern "C" void kernel_launch(void* const* d_in, const int* in_sizes, int n_in,
                              void* d_out, int out_size, void* d_ws, size_t ws_size,
                              hipStream_t stream) {
  const float* x   = (const float*)d_in[0];
  const float* pos = (const float*)d_in[1];
  const int*   ei  = (const int*)d_in[2];
  const float* w1  = (const float*)d_in[3];
  const float* b1  = (const float*)d_in[4];
  const float* w2  = (const float*)d_in[5];
  const float* b2  = (const float*)d_in[6];
  const float* w3  = (const float*)d_in[7];
  const float* b3  = (const float*)d_in[8];
  const float* w4  = (const float*)d_in[9];
  const float* b4  = (const float*)d_in[10];
  const float* w5  = (const float*)d_in[11];
  const float* b5  = (const float*)d_in[12];
  float* out = (float*)d_out;

  const int N = in_sizes[0] / 3;
  const int E = in_sizes[2] / 2;

  char* ws = (char*)d_ws;
  float* agg = (float*)ws;                                    // N*128 f32
  const size_t aggBytes = (size_t)N * NHID * sizeof(float);
  int*  cnt    = (int*)(ws + aggBytes);                       // N ints
  int2* sorted = (int2*)(ws + aggBytes + (size_t)N * 4);      // E int2
  int*  bsums  = (int*)(ws + aggBytes + (size_t)N * 4 + (size_t)E * 8);
  int*  flag   = bsums + 1024;
  const size_t needed = aggBytes + (size_t)N * 4 + (size_t)E * 8 + 1024 * 4 + 16;
  const int nbA = (N + 1023) / 1024;

  if (ws_size >= needed && nbA <= 256) {
    zero_cnt_detect_kernel<<<256, 256, 0, stream>>>(cnt, N, ei, flag);
    hist_zero_kernel<<<2048, 256, 0, stream>>>(ei, flag, cnt, E, (float4*)agg, N * 32);
    scan_a<<<nbA, 256, 0, stream>>>(cnt, bsums, N);
    scan_b<<<1, 256, 0, stream>>>(bsums, nbA);
    scatter_kernel<<<2048, 256, 0, stream>>>(ei, flag, cnt, bsums, sorted, E);
    edge_sorted_kernel<<<512, 512, 0, stream>>>(x, sorted, w1, b1, w2, b2, agg, N, E);
  } else {
    int* flag2 = (int*)(ws + aggBytes);
    zero_detect_kernel<<<2048, 256, 0, stream>>>((float4*)agg, N * NHID / 4, ei, flag2);
    edge_atomic_kernel<<<512, 256, 0, stream>>>(x, ei, w1, b1, w2, b2, agg, flag2, N, E);
  }
  encdec_kernel<<<512, 256, 0, stream>>>(w3, b3, w4, b4, w5, b5, pos, agg, out, N);
}